// Round 22
// baseline (422.370 us; speedup 1.0000x reference)
//
#include <hip/hip_runtime.h>
#include <hip/hip_bf16.h>
#include <math.h>

#define BB 4
#define TT 512
#define HID 2048
#define NH 6
#define DK 256
#define DV 512
#define ROWS (BB*TT)          /* 2048 */
#define KEY_DIM (NH*DK)       /* 1536 */
#define VAL_DIM (NH*DV)       /* 3072 */
#define NG (BB*NH)            /* 24 groups */
#define NC 8                  /* chunks */
#define CL 64                 /* chunk length */
#define QW 9344               /* fused row stride: q|k|v|gate|a|b|pad */
#define OFF_K 1536
#define OFF_V 3072
#define OFF_G 6144
#define OFF_A 9216

typedef __bf16 bf16x8 __attribute__((ext_vector_type(8)));
typedef float  f32x4  __attribute__((ext_vector_type(4)));

__device__ __forceinline__ unsigned short f2bf(float f) {
    unsigned int u = __float_as_uint(f);
    u = (u + 0x7FFFu + ((u >> 16) & 1u)) >> 16;
    return (unsigned short)u;
}
__device__ __forceinline__ float b2f(unsigned short u) {
    return __uint_as_float(((unsigned int)u) << 16);
}

// ---------------------------------------------------------------------------
// fp32 -> bf16 cast (RNE), vectorized. Single-source variant (Wo).
// ---------------------------------------------------------------------------
__global__ __launch_bounds__(256) void cast_f32_bf16(
    const float* __restrict__ src, unsigned short* __restrict__ dst, int n4)
{
    int stride = gridDim.x * 256;
    for (int i = blockIdx.x * 256 + threadIdx.x; i < n4; i += stride) {
        float4 v = ((const float4*)src)[i];
        ushort4 o;
        o.x = f2bf(v.x); o.y = f2bf(v.y); o.z = f2bf(v.z); o.w = f2bf(v.w);
        ((ushort4*)dst)[i] = o;
    }
}

// ---------------------------------------------------------------------------
// Multi-source fp32 -> bf16 cast: 8 sources (nullptr -> zero fill), one
// contiguous destination. Builds x | Wq | Wk | Wv | Wg | Wa | Wb | 0-pad.
// ---------------------------------------------------------------------------
struct Cast8 {
    const float* src[8];
    int start4[9];           // cumulative float4 offsets into dst
};
__global__ __launch_bounds__(256) void cast_multi(Cast8 c, unsigned short* __restrict__ dst)
{
    const int total = c.start4[8];
    int stride = gridDim.x * 256;
    for (int i = blockIdx.x * 256 + threadIdx.x; i < total; i += stride) {
        int s = 0;
        while (i >= c.start4[s + 1]) ++s;
        float4 v = make_float4(0.f, 0.f, 0.f, 0.f);
        if (c.src[s]) v = ((const float4*)c.src[s])[i - c.start4[s]];
        ushort4 o;
        o.x = f2bf(v.x); o.y = f2bf(v.y); o.z = f2bf(v.z); o.w = f2bf(v.w);
        ((ushort4*)dst)[i] = o;
    }
}

// ---------------------------------------------------------------------------
// out = p0+p1+p2+p3 (bf16 partials, fp32 sum/store; deterministic order).
// ---------------------------------------------------------------------------
__global__ __launch_bounds__(256) void add4_bf16(
    float* __restrict__ out, const unsigned short* __restrict__ p0,
    const unsigned short* __restrict__ p1, const unsigned short* __restrict__ p2,
    const unsigned short* __restrict__ p3, int n4)
{
    int stride = gridDim.x * 256;
    for (int i = blockIdx.x * 256 + threadIdx.x; i < n4; i += stride) {
        ushort4 a = ((const ushort4*)p0)[i];
        ushort4 b = ((const ushort4*)p1)[i];
        ushort4 c = ((const ushort4*)p2)[i];
        ushort4 d = ((const ushort4*)p3)[i];
        float4 o;
        o.x = ((b2f(a.x) + b2f(b.x)) + b2f(c.x)) + b2f(d.x);
        o.y = ((b2f(a.y) + b2f(b.y)) + b2f(c.y)) + b2f(d.y);
        o.z = ((b2f(a.z) + b2f(b.z)) + b2f(c.z)) + b2f(d.z);
        o.w = ((b2f(a.w) + b2f(b.w)) + b2f(c.w)) + b2f(d.w);
        ((float4*)out)[i] = o;
    }
}

// ---------------------------------------------------------------------------
// QKVG fused-projection GEMM v3: BARRIER-FREE wave-private pipeline.
// 1 wave per block (64 threads), 64x64 tile, BK=32. Each wave owns its own
// 4-buffer LDS ring (4 x (4KB A + 4KB B) = 32KB) -> no __syncthreads at all;
// the only waits are per-wave counted s_waitcnt vmcnt(16) (never 0 in the
// main loop). This removes the 2-phase barrier-drain stall structurally:
// correctness is wave-local (wave waits only on its own global_load_lds).
// WAR safety on the ring: iter-s ds_reads are lgkm-drained before iter-s
// MFMAs consume them, which precede the iter-(s+1) overwrite of the same
// buffer in program order; sched_barrier(0) pins ds_read issue order.
// Per-output accumulation order identical to v2 -> bit-identical C.
// Grid (M/64)x(N/64) = 4672 (%8==0), XCD-chunked: bm fast-varying, B-tile
// (256KB) L2-resident per XCD, A served from L3.
// a/b cols (OFF_A..+11) side-stored fp32 as before.
// ---------------------------------------------------------------------------
__global__ __launch_bounds__(64) void gemm_qkvg(
    const unsigned short* __restrict__ A, const unsigned short* __restrict__ B,
    unsigned short* __restrict__ C, float* __restrict__ ab32, int M, int N, int K)
{
    __shared__ __align__(16) unsigned short As[4][64 * 32];   // 4 x 4KB
    __shared__ __align__(16) unsigned short Bs[4][64 * 32];   // 4 x 4KB
    const int lane = threadIdx.x;        // 0..63
    const int per  = gridDim.x >> 3;     // 584
    const int lg   = (blockIdx.x & 7) * per + (blockIdx.x >> 3);
    const int bm = (lg & 31) * 64;       // M = 2048 -> 32 tiles, fast-varying
    const int bn = (lg >> 5) * 64;       // N = 9344 -> 146 tiles, per-XCD chunk
    const int fr = lane & 15;
    const int kg = lane >> 4;

    f32x4 acc[4][4] = {};

    // stage one 32-k step: 64x32 bf16 per matrix = 256 x 16B chunks, 4/lane.
    // chunk ch: row = ch>>2, k-subchunk = ch&3 (coalesced: 4 lanes cover a
    // row's 64B). Dest = linear [row][32] layout.
#define STAGE(buf, kk) do { \
    int k0_ = (kk) * 32; \
    _Pragma("unroll") \
    for (int it_ = 0; it_ < 4; ++it_) { \
        int ch_ = it_ * 64 + lane; \
        int r_  = ch_ >> 2; \
        int c8_ = (ch_ & 3) * 8; \
        const unsigned short* ga_ = A + (size_t)(bm + r_) * K + k0_ + c8_; \
        const unsigned short* gb_ = B + (size_t)(bn + r_) * K + k0_ + c8_; \
        __builtin_amdgcn_global_load_lds( \
            (const __attribute__((address_space(1))) void*)ga_, \
            (__attribute__((address_space(3))) void*)&As[buf][(size_t)ch_ * 8], 16, 0, 0); \
        __builtin_amdgcn_global_load_lds( \
            (const __attribute__((address_space(1))) void*)gb_, \
            (__attribute__((address_space(3))) void*)&Bs[buf][(size_t)ch_ * 8], 16, 0, 0); \
    } \
} while (0)

    const int nsteps = K >> 5;           // 64
    STAGE(0, 0);                         // prologue: 3 stages = 24 loads
    STAGE(1, 1);
    STAGE(2, 2);

    for (int s = 0; s < nsteps; ++s) {
        const int buf = s & 3;
        // wait ONLY until stage s's 8 loads are done (per-wave counted)
        if (s + 2 < nsteps) {
            asm volatile("s_waitcnt vmcnt(16)" ::: "memory");
        } else if (s + 1 < nsteps) {
            asm volatile("s_waitcnt vmcnt(8)" ::: "memory");
        } else {
            asm volatile("s_waitcnt vmcnt(0)" ::: "memory");
        }

        bf16x8 a[4], b[4];
        #pragma unroll
        for (int f = 0; f < 4; ++f) {
            a[f] = *(const bf16x8*)&As[buf][(f * 16 + fr) * 32 + kg * 8];
            b[f] = *(const bf16x8*)&Bs[buf][(f * 16 + fr) * 32 + kg * 8];
        }
        __builtin_amdgcn_sched_barrier(0);   // pin: ds_reads issued before stage

        if (s + 3 < nsteps) STAGE((s + 3) & 3, s + 3);   // stays in flight

        #pragma unroll
        for (int fm = 0; fm < 4; ++fm)
            #pragma unroll
            for (int fn = 0; fn < 4; ++fn)
                acc[fm][fn] = __builtin_amdgcn_mfma_f32_16x16x32_bf16(
                    a[fm], b[fn], acc[fm][fn], 0, 0, 0);
    }
#undef STAGE

    #pragma unroll
    for (int fm = 0; fm < 4; ++fm)
        #pragma unroll
        for (int fn = 0; fn < 4; ++fn) {
            int col = bn + fn * 16 + fr;
            bool isab = (col >= OFF_A) && (col < OFF_A + 12);
            #pragma unroll
            for (int i = 0; i < 4; ++i) {
                int row = bm + fm * 16 + kg * 4 + i;
                float v = acc[fm][fn][i];
                C[(size_t)row * N + col] = f2bf(v);
                if (isab) ab32[(size_t)row * 12 + (col - OFF_A)] = v;
            }
        }
}

// ---------------------------------------------------------------------------
// Split-K=4 GEMM for the grid-starved Wo projection (M=2048,N=2048,K=3072):
// ONE dispatch, 1024 blocks. All four K-quarters store bf16 partials
// (P0..P3); add4_bf16 sums them in fp32 (deterministic).
// [Kept in the 2-phase 128^2 form as in-round control vs the new qkvg.]
// ---------------------------------------------------------------------------
__global__ __launch_bounds__(256) void gemm_nt_splitk4(
    const unsigned short* __restrict__ A, const unsigned short* __restrict__ B,
    unsigned short* __restrict__ C0, unsigned short* __restrict__ C1,
    unsigned short* __restrict__ C2, unsigned short* __restrict__ C3,
    int M, int N, int K)
{
    __shared__ __align__(16) unsigned short As[2][128 * 32];
    __shared__ __align__(16) unsigned short Bs[2][128 * 32];
    const int tid  = threadIdx.x;
    const int lane = tid & 63;
    const int wave = tid >> 6;
    const int per  = gridDim.x >> 3;
    const int lg   = (blockIdx.x & 7) * per + (blockIdx.x >> 3);
    const int kh   = lg & 3;
    const int bmn  = lg >> 2;
    const int bm = (bmn & 15) * 128;
    const int bn = (bmn >> 4) * 128;
    const int wr = (wave >> 1) * 64;
    const int wc = (wave & 1) * 64;
    const int fr = lane & 15;
    const int kg = lane >> 4;
    const int Kq = K >> 2;               // 768 -> 24 steps
    const int kbase = kh * Kq;

    f32x4 acc[4][4] = {};

#define GSTAGE(buf, k0) do { \
    _Pragma("unroll") \
    for (int s_ = 0; s_ < 2; ++s_) { \
        int e_  = s_ * 256 + tid; \
        int r_  = e_ >> 2; \
        int c8_ = (e_ & 3) * 8; \
        const unsigned short* ga_ = A + (size_t)(bm + r_) * K + (k0) + c8_; \
        const unsigned short* gb_ = B + (size_t)(bn + r_) * K + (k0) + c8_; \
        unsigned short* la_ = As[buf] + (size_t)(s_ * 256 + wave * 64) * 8; \
        unsigned short* lb_ = Bs[buf] + (size_t)(s_ * 256 + wave * 64) * 8; \
        __builtin_amdgcn_global_load_lds( \
            (const __attribute__((address_space(1))) void*)ga_, \
            (__attribute__((address_space(3))) void*)la_, 16, 0, 0); \
        __builtin_amdgcn_global_load_lds( \
            (const __attribute__((address_space(1))) void*)gb_, \
            (__attribute__((address_space(3))) void*)lb_, 16, 0, 0); \
    } \
} while (0)

    GSTAGE(0, kbase);
    __syncthreads();

    int cur = 0;
    for (int k0 = kbase; k0 < kbase + Kq; k0 += 32) {
        if (k0 + 32 < kbase + Kq) GSTAGE(cur ^ 1, k0 + 32);

        bf16x8 a[4], b[4];
        #pragma unroll
        for (int f = 0; f < 4; ++f) {
            a[f] = *(const bf16x8*)&As[cur][(wr + f * 16 + fr) * 32 + kg * 8];
            b[f] = *(const bf16x8*)&Bs[cur][(wc + f * 16 + fr) * 32 + kg * 8];
        }
        #pragma unroll
        for (int fm = 0; fm < 4; ++fm)
            #pragma unroll
            for (int fn = 0; fn < 4; ++fn)
                acc[fm][fn] = __builtin_amdgcn_mfma_f32_16x16x32_bf16(
                    a[fm], b[fn], acc[fm][fn], 0, 0, 0);

        __syncthreads();
        cur ^= 1;
    }
#undef GSTAGE

    unsigned short* C = (kh == 0) ? C0 : (kh == 1) ? C1 : (kh == 2) ? C2 : C3;
    #pragma unroll
    for (int fm = 0; fm < 4; ++fm)
        #pragma unroll
        for (int fn = 0; fn < 4; ++fn) {
            int col = bn + wc + fn * 16 + fr;
            #pragma unroll
            for (int i = 0; i < 4; ++i) {
                int row = bm + wr + fm * 16 + kg * 4 + i;
                C[(size_t)row * N + col] = f2bf(acc[fm][fn][i]);
            }
        }
}

// ---------------------------------------------------------------------------
// Per-group: a/b (fp32 side-store) -> g, beta; cumulative log-decay scan;
// writes cinc/cexc/barr. 24 blocks x 64 threads.
// ---------------------------------------------------------------------------
__global__ __launch_bounds__(64) void cumsum_pack(
    const float* __restrict__ ab32,
    const float* __restrict__ A_log, const float* __restrict__ dt_bias,
    float* __restrict__ cinc, float* __restrict__ cexc, float* __restrict__ barr)
{
    const int g = blockIdx.x;
    const int b = g / NH, h = g % NH;
    const int lane = threadIdx.x;
    const float nA = -expf(A_log[h]);
    const float db = dt_bias[h];
    float carry = 0.f;
    for (int c0 = 0; c0 < TT; c0 += 64) {
        int t = c0 + lane;
        size_t rbase = (size_t)(b*TT + t) * 12;
        float a  = ab32[rbase + h] + db;
        float sp = (a > 20.f) ? a : log1pf(expf(a));
        float gv = nA * sp;
        float bp = ab32[rbase + 6 + h];
        float x = gv;
        #pragma unroll
        for (int off = 1; off < 64; off <<= 1) {
            float n = __shfl_up(x, off);
            if (lane >= off) x += n;
        }
        float inc = carry + x;
        cinc[(size_t)g*TT + t] = inc;
        cexc[(size_t)g*TT + t] = inc - gv;
        barr[(size_t)g*TT + t] = 1.f / (1.f + expf(-bp));
        carry = __shfl(inc, 63);
    }
}

// ---------------------------------------------------------------------------
// Pointwise prep v2: barrier-free. 384 threads = 6 waves; wave h owns head h.
// ---------------------------------------------------------------------------
__global__ __launch_bounds__(384) void prep_norm(
    const unsigned short* __restrict__ qkvg,
    const float* __restrict__ decay, const float* __restrict__ D,
    const float* __restrict__ barr,
    unsigned short* __restrict__ qb, unsigned short* __restrict__ kb,
    unsigned short* __restrict__ bvb)
{
    const int row  = blockIdx.x;
    const int b    = row >> 9, t = row & 511;
    const int tid  = threadIdx.x;
    const int h    = tid >> 6;       // wave = head
    const int lane = tid & 63;

    size_t base = (size_t)row * QW + h * DK + lane * 4;
    ushort4 qu = *(const ushort4*)&qkvg[base];
    ushort4 ku = *(const ushort4*)&qkvg[base + OFF_K];
    float qv[4] = {b2f(qu.x), b2f(qu.y), b2f(qu.z), b2f(qu.w)};
    float kv[4] = {b2f(ku.x), b2f(ku.y), b2f(ku.z), b2f(ku.w)};
    const float coef = D[h] * (1.f / (1.f + expf(-decay[h])));
    float qc[4], kl[4];
    float sq = 0.f, sk = 0.f;
    #pragma unroll
    for (int i = 0; i < 4; ++i) {
        float ksil = kv[i] / (1.f + expf(-kv[i]));
        float qsil = qv[i] / (1.f + expf(-qv[i]));
        qc[i] = qsil - coef * ksil;
        kl[i] = ksil;
        sq += qc[i] * qc[i];
        sk += ksil * ksil;
    }
    #pragma unroll
    for (int off = 32; off >= 1; off >>= 1) {
        sq += __shfl_xor(sq, off);
        sk += __shfl_xor(sk, off);
    }
    float qinv = 0.0625f / fmaxf(sqrtf(sq), 1e-12f);
    float kinv = 1.f     / fmaxf(sqrtf(sk), 1e-12f);
    size_t gidx = (((size_t)(b*NH + h)) * TT + t) * DK + lane * 4;
    ushort4 qo, ko;
    qo.x = f2bf(qc[0]*qinv); qo.y = f2bf(qc[1]*qinv);
    qo.z = f2bf(qc[2]*qinv); qo.w = f2bf(qc[3]*qinv);
    ko.x = f2bf(kl[0]*kinv); ko.y = f2bf(kl[1]*kinv);
    ko.z = f2bf(kl[2]*kinv); ko.w = f2bf(kl[3]*kinv);
    *(ushort4*)&qb[gidx] = qo;
    *(ushort4*)&kb[gidx] = ko;

    const int jj0 = tid * 8;
    const int h2  = jj0 >> 9;
    const int dv  = jj0 & 511;
    float bt = barr[((size_t)(b*NH + h2)) * TT + t];
    const unsigned short* vp = &qkvg[(size_t)row * QW + OFF_V + jj0];
    unsigned short* bp = &bvb[(((size_t)(b*NH + h2)) * TT + t) * DV + dv];
    ushort4 v0 = *(const ushort4*)vp;
    ushort4 v1 = *(const ushort4*)(vp + 4);
    unsigned short vi[8] = {v0.x, v0.y, v0.z, v0.w, v1.x, v1.y, v1.z, v1.w};
    ushort4 o0, o1;
    unsigned short vo[8];
    #pragma unroll
    for (int i = 0; i < 8; ++i) {
        float xv = b2f(vi[i]);
        float sv = xv / (1.f + expf(-xv));
        vo[i] = f2bf(bt * sv);
    }
    o0.x = vo[0]; o0.y = vo[1]; o0.z = vo[2]; o0.w = vo[3];
    o1.x = vo[4]; o1.y = vo[5]; o1.z = vo[6]; o1.w = vo[7];
    *(ushort4*)bp       = o0;
    *(ushort4*)(bp + 4) = o1;
}

// ---------------------------------------------------------------------------
// A-matrix tiles: A[i,j] = beta_i * exp(cexc_i - cinc_j) * (k_i . k_j), j<i.
// Diagonal blocks (l==m) ALSO compute the unit-lower-triangular inverse of
// (I + A_mm) in-kernel (fused minv).
// ---------------------------------------------------------------------------
__global__ __launch_bounds__(256) void a_mat(
    const unsigned short* __restrict__ kb, const float* __restrict__ cinc,
    const float* __restrict__ cexc, const float* __restrict__ barr,
    unsigned short* __restrict__ Ab, unsigned short* __restrict__ Minvb)
{
    __shared__ __align__(16) unsigned short Asub[64][72];
    __shared__ __align__(16) float Xt[64][68];

    const int blk = blockIdx.x;
    const int g = blk / 36;
    int p = blk % 36, m = 0, acc0 = 0;
    while (p >= acc0 + m + 1) { acc0 += m + 1; ++m; }
    const int l = p - acc0;
    const int tid = threadIdx.x, lane = tid & 63, w = tid >> 6;
    const int fr = lane & 15, kg = lane >> 4;
    const unsigned short* Km = kb + (((size_t)g*TT) + m*CL) * DK;
    const unsigned short* Kl = kb + (((size_t)g*TT) + l*CL) * DK;
    f32x4 acc[4] = {};
    #pragma unroll
    for (int ks = 0; ks < 8; ++ks) {
        bf16x8 a = *(const bf16x8*)(Km + (size_t)(w*16 + fr)*DK + ks*32 + kg*8);
        bf16x8 bb[4];
        #pragma unroll
        for (int fn = 0; fn < 4; ++fn)
            bb[fn] = *(const bf16x8*)(Kl + (size_t)(fn*16 + fr)*DK + ks*32 + kg*8);
        #pragma unroll
        for (int fn = 0; fn < 4; ++fn)
            acc[fn] = __builtin_amdgcn_mfma_f32_16x16x32_bf16(a, bb[fn], acc[fn], 0, 0, 0);
    }
    const float* ci = cinc + (size_t)g*TT;
    const float* ce = cexc + (size_t)g*TT;
    const float* bb2 = barr + (size_t)g*TT;
    const bool diag = (l == m);
    #pragma unroll
    for (int fn = 0; fn < 4; ++fn) {
        int jl = fn*16 + fr;
        int tj = l*CL + jl;
        float cj = ci[tj];
        #pragma unroll
        for (int r = 0; r < 4; ++r) {
            int il = w*16 + kg*4 + r;
            int ti = m*CL + il;
            float val = 0.f;
            if (tj < ti) val = bb2[ti] * __expf(ce[ti] - cj) * acc[fn][r];
            unsigned short vb = f2bf(val);
            Ab[((size_t)g*TT + ti)*TT + tj] = vb;
            if (diag) Asub[il][jl] = vb;
        }
    }

    if (diag) {
        __syncthreads();                 // Asub staged by all 4 waves
        if (tid < 64) {                  // wave 0: wave-synchronous inverse
            const int col = tid;
            #pragma unroll
            for (int t4 = 0; t4 < 17; ++t4)
                *(float4*)&Xt[col][t4*4] = make_float4(0.f, 0.f, 0.f, 0.f);
            Xt[col][col] = 1.f;
            #pragma unroll 1
            for (int i = 1; i < 64; ++i) {
                const int nch = (i + 7) >> 3;
                float s = 0.f;
                #pragma unroll 1
                for (int c8 = 0; c8 < nch; ++c8) {
                    ushort4 a0 = *(const ushort4*)&Asub[i][c8*8];
                    ushort4 a1 = *(const ushort4*)&Asub[i][c8*8 + 4];
                    float4  x0 = *(const float4*)&Xt[col][c8*8];
                    float4  x1 = *(const float4*)&Xt[col][c8*8 + 4];
                    s += b2f(a0.x)*x0.x; s += b2f(a0.y)*x0.y;
                    s += b2f(a0.z)*x0.z; s += b2f(a0.w)*x0.w;
                    s += b2f(a1.x)*x1.x; s += b2f(a1.y)*x1.y;
                    s += b2f(a1.z)*x1.z; s += b2f(a1.w)*x1.w;
                }
                if (col < i) Xt[col][i] = -s;
            }
            unsigned short* outp = Minvb + (size_t)(g*8 + m) * 4096;
            #pragma unroll 4
            for (int r = 0; r < 64; ++r)
                outp[(size_t)r*64 + col] = f2bf(Xt[col][r]);
        }
    }
}

// ---------------------------------------------------------------------------
// U-solve v3: (I+A) U = beta*V, block forward substitution over 8 chunks.
// grid = 24 groups x 16 v-slices(32) = 384 blocks. Utb[g][v][t] bf16.
// Block's whole U slice mirrored in LDS (Uls[32][520]); all chunk-to-chunk
// U reads come from LDS (no global RAW round-trips). Bit-identical.
// ---------------------------------------------------------------------------
__global__ __launch_bounds__(256) void usolve(
    const unsigned short* __restrict__ Ab, const unsigned short* __restrict__ Minvb,
    const unsigned short* __restrict__ bvb, unsigned short* __restrict__ Utb)
{
    const int blk = blockIdx.x;
    const int g = blk >> 4, vs = blk & 15;
    const int tid = threadIdx.x, lane = tid & 63, w = tid >> 6;
    const int fr = lane & 15, kg = lane >> 4;
    __shared__ __align__(16) unsigned short TACC[2][32][40];
    __shared__ __align__(16) unsigned short Uls[32][520];   // [v][t], pad->2-way

    for (int m = 0; m < NC; ++m) {
        f32x4 acc[2] = {};
        for (int l = 0; l < m; ++l) {
            const unsigned short* Aml = Ab + (((size_t)g*TT) + m*CL)*TT + l*CL;
            #pragma unroll
            for (int ks = 0; ks < 2; ++ks) {
                bf16x8 a = *(const bf16x8*)(Aml + (size_t)(w*16 + fr)*TT + ks*32 + kg*8);
                bf16x8 bb[2];
                #pragma unroll
                for (int fn = 0; fn < 2; ++fn)
                    bb[fn] = *(const bf16x8*)&Uls[fn*16 + fr][l*CL + ks*32 + kg*8];
                #pragma unroll
                for (int fn = 0; fn < 2; ++fn)
                    acc[fn] = __builtin_amdgcn_mfma_f32_16x16x32_bf16(a, bb[fn], acc[fn], 0, 0, 0);
            }
        }
        __syncthreads();
        const unsigned short* bvg = bvb + (((size_t)g*TT) + m*CL)*DV + vs*32;
        #pragma unroll
        for (int fn = 0; fn < 2; ++fn) {
            int v = fn*16 + fr;
            #pragma unroll
            for (int r = 0; r < 4; ++r) {
                int i = w*16 + kg*4 + r;
                float rhs = b2f(bvg[(size_t)i*DV + v]) - acc[fn][r];
                TACC[i >> 5][v][i & 31] = f2bf(rhs);
            }
        }
        __syncthreads();
        const unsigned short* Mi = Minvb + (size_t)(g*8 + m) * 4096;
        f32x4 acc2[2] = {};
        #pragma unroll
        for (int ks = 0; ks < 2; ++ks) {
            bf16x8 a = *(const bf16x8*)(Mi + (size_t)(w*16 + fr)*64 + ks*32 + kg*8);
            bf16x8 bb[2];
            #pragma unroll
            for (int fn = 0; fn < 2; ++fn)
                bb[fn] = *(const bf16x8*)&TACC[ks][fn*16 + fr][kg*8];
            #pragma unroll
            for (int fn = 0; fn < 2; ++fn)
                acc2[fn] = __builtin_amdgcn_mfma_f32_16x16x32_bf16(a, bb[fn], acc2[fn], 0, 0, 0);
        }
        unsigned short* Um = Utb + (((size_t)g*TT) + vs*32)*TT + m*CL;
        #pragma unroll
        for (int fn = 0; fn < 2; ++fn) {
            int v = fn*16 + fr;
            #pragma unroll
            for (int r = 0; r < 4; ++r) {
                int i = w*16 + kg*4 + r;
                unsigned short uv = f2bf(acc2[fn][r]);
                Um[(size_t)v*TT + i] = uv;          // for o_kern
                Uls[v][m*CL + i]    = uv;           // for later chunks (LDS)
            }
        }
        __syncthreads();   // LDS U-chunk visible before next chunk reads it
    }
}

// ---------------------------------------------------------------------------
// Output: o_i = sum_{j<=i} exp(c_i - c_j)*(q_i . k_j) * u_j.
// Block = (g, m-pair {p, 7-p}, v-quarter 128). 9 balanced l-iters per block.
// K/U tiles async-staged into double-buffered swizzled LDS; Q in registers.
// Writes o bf16 into the fused qkvg buffer's (dead) v columns @3072.
// ---------------------------------------------------------------------------
__global__ __launch_bounds__(256) void o_kern(
    const unsigned short* __restrict__ qb, const unsigned short* __restrict__ kb,
    const unsigned short* __restrict__ Utb, const float* __restrict__ cinc,
    unsigned short* __restrict__ qkvg)
{
    __shared__ __align__(16) unsigned short Kls[2][64*256];   // 64 KB
    __shared__ __align__(16) unsigned short Uls[2][128*64];   // 32 KB
    __shared__ __align__(16) unsigned short Ps[2][64][40];    // 10 KB
    __shared__ float cgl[TT];                                 // 2 KB

    const int blk = blockIdx.x;
    const int g  = blk >> 4;
    const int rm = blk & 15;
    const int pr = rm >> 2;
    const int vq = rm & 3;
    const int b = g / NH, h = g % NH;
    const int tid = threadIdx.x, lane = tid & 63, w = tid >> 6;
    const int fr = lane & 15, kg = lane >> 4;

    const unsigned short* kgrp = kb  + (size_t)g*TT*DK;
    const unsigned short* ugrp = Utb + ((size_t)g*TT + vq*128)*TT;

#define STAGE_K(buf, l) do { \
    _Pragma("unroll") \
    for (int s_ = 0; s_ < 8; ++s_) { \
        int slot_ = s_*256 + tid; \
        int gc_ = slot_ ^ ((slot_ >> 5) & 7); \
        const unsigned short* ga_ = kgrp + (size_t)(l)*CL*DK + gc_*8; \
        __builtin_amdgcn_global_load_lds( \
            (const __attribute__((address_space(1))) void*)ga_, \
            (__attribute__((address_space(3))) void*)&Kls[buf][slot_*8], 16, 0, 0); \
    } \
} while (0)

#define STAGE_U(buf, l) do { \
    _Pragma("unroll") \
    for (int s_ = 0; s_ < 4; ++s_) { \
        int slot_ = s_*256 + tid; \
        int gc_ = slot_ ^ ((slot_ >> 3) & 7); \
        const unsigned short* ga_ = ugrp + (size_t)(gc_ >> 3)*TT + (l)*CL + (gc_ & 7)*8; \
        __builtin_amdgcn_global_load_lds( \
            (const __attribute__((address_space(1))) void*)ga_, \
            (__attribute__((address_space(3))) void*)&Uls[buf][slot_*8], 16, 0, 0); \
    } \
} while (0)

    cgl[tid]       = cinc[(size_t)g*TT + tid];
    cgl[tid + 256] = cinc[(size_t)g*TT + tid + 256];
    STAGE_K(0, 0);
    STAGE_U(0, 0);
    __syncthreads();

    int cur = 0;
    #pragma unroll 1
    for (int mi_idx = 0; mi_idx < 2; ++mi_idx) {
        const int mi = mi_idx ? (7 - pr) : pr;
        const unsigned short* Qm = qb + (((size_t)g*TT) + mi*CL) * DK + (size_t)(w*16 + fr)*DK;
        bf16x8 qf[8];
        #pragma unroll
        for (int ks = 0; ks < 8; ++ks) qf[ks] = *(const bf16x8*)(Qm + ks*32 + kg*8);

        f32x4 acc[8] = {};
        #pragma unroll 1
        for (int l = 0; l <= mi; ++l) {
            if (l < mi)            { STAGE_K(cur^1, l+1); STAGE_U(cur^1, l+1); }
            else if (mi_idx == 0)  { STAGE_K(cur^1, 0);   STAGE_U(cur^1, 0);   }

            f32x4 sacc[4] = {};
            #pragma unroll
            for (int ks = 0; ks < 8; ++ks) {
                bf16x8 bbf[4];
                #pragma unroll
                for (int fn = 0; fn < 4; ++fn) {
                    int row = fn*16 + fr;
                    int slot = (row*32 + ks*4 + kg) ^ (row & 7);
                    bbf[fn] = *(const bf16x8*)&Kls[cur][slot*8];
                }
                #pragma unroll
                for (int fn = 0; fn < 4; ++fn)
                    sacc[fn] = __builtin_amdgcn_mfma_f32_16x16x32_bf16(qf[ks], bbf[fn], sacc[fn], 0, 0, 0);
            }
            __syncthreads();

            #pragma unroll
            for (int fn = 0; fn < 4; ++fn) {
                int jl = fn*16 + fr;
                float cjv = cgl[l*CL + jl];
                #pragma unroll
                for (int r = 0; r < 4; ++r) {
                    int il = w*16 + kg*4 + r;
                    float val = ((l*CL + jl) <= (mi*CL + il))
                              ? sacc[fn][r] * __expf(cgl[mi*CL + il] - cjv) : 0.f;
                    Ps[jl >> 5][il][jl & 31] = f2bf(val);
                }
            }
            __syncthreads();

            #pragma unroll
            for (int ks = 0; ks < 2; ++ks) {
                bf16x8 a = *(const bf16x8*)&Ps[ks][w*16 + fr][kg*8];
                bf16x8 bbf[8];
                #pragma unroll
                for (int fn = 0; fn < 8; ++fn) {
                    int vrow = fn*16 + fr;
                    int slot = (vrow*8 + ks*4 + kg) ^ (vrow & 7);
                    bbf[fn] = *(const bf16x8*)&Uls[cur][slot*8];
                }
                #pragma unroll
                for (int fn = 0; fn < 8; ++fn)
                    acc[fn] = __builtin_amdgcn_mfma_f32_16x16x32_bf16(a, bbf[fn], acc[fn], 0, 0, 0);
            }
            __syncthreads();
            cur ^= 1;
        }

        // store o (bf16) into fused buffer (dead v columns): [row][QW]@3072
        unsigned short* ob = qkvg + ((size_t)(b*TT + mi*CL)) * QW + OFF_V + h*DV + vq*128;
        #pragma unroll
        for (int fn = 0; fn < 8; ++fn) {
            int v = fn*16 + fr;
            #pragma unroll
            for (int r = 0; r < 4; ++r) {
                int il = w*16 + kg*4 + r;
                ob[(size_t)il*QW + v] = f2bf(acc[fn][r]);
            }
        }
    }
#undef STAGE_K
#undef STAGE_U
}

// ---------------------------------------------------------------------------
// Gated RMSNorm epilogue v2: barrier-free. 384 threads = 6 waves; wave h owns
// head h: 8 elems/lane, wave-local shfl reduction, 16B loads/stores.
// ---------------------------------------------------------------------------
__global__ __launch_bounds__(384) void epilogue(
    const unsigned short* __restrict__ qkvg, const float* __restrict__ wnorm,
    unsigned short* __restrict__ ob)
{
    const int row  = blockIdx.x;
    const int tid  = threadIdx.x;
    const int h    = tid >> 6;
    const int lane = tid & 63;

    size_t base = (size_t)row * QW + OFF_V + h * DV + lane * 8;
    ushort4 a0 = *(const ushort4*)&qkvg[base];
    ushort4 a1 = *(const ushort4*)&qkvg[base + 4];
    unsigned short oi[8] = {a0.x, a0.y, a0.z, a0.w, a1.x, a1.y, a1.z, a1.w};
    float ov[8];
    float ss = 0.f;
    #pragma unroll
    for (int i = 0; i < 8; ++i) { ov[i] = b2f(oi[i]); ss += ov[i]*ov[i]; }
    #pragma unroll
    for (int off = 32; off >= 1; off >>= 1) ss += __shfl_xor(ss, off);
    float irms = rsqrtf(ss * (1.f / DV) + 1e-6f);

    size_t gbase = (size_t)row * QW + OFF_G + h * DV + lane * 8;
    ushort4 g0 = *(const ushort4*)&qkvg[gbase];
    ushort4 g1 = *(const ushort4*)&qkvg[gbase + 4];
    unsigned short gi[8] = {g0.x, g0.y, g0.z, g0.w, g1.x, g1.y, g1.z, g1.w};

    unsigned short vo[8];
    #pragma unroll
    for (int i = 0; i < 8; ++i) {
        float gv = b2f(gi[i]);
        float wv = wnorm[lane*8 + i];
        vo[i] = f2bf(ov[i] * irms * wv * (1.f / (1.f + expf(-gv))));
    }
    size_t obase = (size_t)row * VAL_DIM + h * DV + lane * 8;
    ushort4 w0, w1;
    w0.x = vo[0]; w0.y = vo[1]; w0.z = vo[2]; w0.w = vo[3];
    w1.x = vo[4]; w1.y = vo[5]; w1.z = vo[6]; w1.w = vo[7];
    *(ushort4*)&ob[obase]     = w0;
    *(ushort4*)&ob[obase + 4] = w1;
}

// ---------------------------------------------------------------------------
extern "C" void kernel_launch(void* const* d_in, const int* in_sizes, int n_in,
                              void* d_out, int out_size, void* d_ws, size_t ws_size,
                              hipStream_t stream)
{
    const float* x     = (const float*)d_in[0];
    const float* Wq    = (const float*)d_in[1];
    const float* Wk    = (const float*)d_in[2];
    const float* Wv    = (const float*)d_in[3];
    const float* Wa    = (const float*)d_in[4];
    const float* Wb    = (const float*)d_in[5];
    const float* decay = (const float*)d_in[6];
    const float* Dp    = (const float*)d_in[7];
    const float* A_log = (const float*)d_in[8];
    const float* dtb   = (const float*)d_in[9];
    const float* Wg    = (const float*)d_in[10];
    const float* Wo    = (const float*)d_in[11];
    const float* onw   = (const float*)d_in[12];
    float* out = (float*)d_out;

    unsigned short* qkvg = (unsigned short*)d_ws;            // ROWS*QW bf16 (38.3 MB)
    float* ab32 = (float*)(qkvg + (size_t)ROWS * QW);        // ROWS*12 fp32 (a|b cols)
    float* cinc = ab32 + (size_t)ROWS * 12;                  // NG*TT
    float* cexc = cinc + (size_t)NG * TT;
    float* barr = cexc + (size_t)NG * TT;
    unsigned short* bf = (unsigned short*)(barr + (size_t)NG * TT);

    // phase 1 (projections): weight block is one contiguous [9344][2048]
    // bf16 matrix (order q,k,v,g,a,b,zero-pad).
    unsigned short* xb  = bf;                                   // ROWS*HID
    unsigned short* Wqb = xb  + (size_t)ROWS * HID;
    // phase R (chunked recurrence) — aliases phase 1 (dead by then)
    unsigned short* qb    = bf;                                 // NG*TT*DK
    unsigned short* kb    = qb  + (size_t)NG*TT*DK;
    unsigned short* bvb   = kb  + (size_t)NG*TT*DK;             // NG*TT*DV
    unsigned short* Ab    = bvb + (size_t)NG*TT*DV;             // NG*TT*TT
    unsigned short* Utb   = Ab  + (size_t)NG*TT*TT;             // NG*TT*TT (transposed)
    unsigned short* Minvb = Utb + (size_t)NG*TT*TT;             // NG*8*64*64
    // phase 2 (output projection): ob aliases qb+kb; Wob aliases bvb;
    // bf16 partials P0..P3 alias Ab onward (dead after o_kern).
    unsigned short* ob  = bf;                                   // ROWS*VAL_DIM
    unsigned short* Wob = bvb;                                  // HID*VAL_DIM
    unsigned short* P0 = Ab;                                    // 4 x ROWS*HID bf16
    unsigned short* P1 = P0 + (size_t)ROWS * HID;
    unsigned short* P2 = P1 + (size_t)ROWS * HID;
    unsigned short* P3 = P2 + (size_t)ROWS * HID;

    dim3 blk(256);
    auto cblocks = [](size_t n) { size_t b = (n / 4 + 255) / 256; return (int)(b > 4096 ? 4096 : b); };

    // fused cast: x|Wq|Wk|Wv|Wg|Wa|Wb|pad -> contiguous bf16 block at xb
    Cast8 c8;
    c8.src[0] = x;  c8.src[1] = Wq; c8.src[2] = Wk; c8.src[3] = Wv;
    c8.src[4] = Wg; c8.src[5] = Wa; c8.src[6] = Wb; c8.src[7] = nullptr;
    c8.start4[0] = 0;
    c8.start4[1] = c8.start4[0] + ROWS*HID/4;
    c8.start4[2] = c8.start4[1] + KEY_DIM*HID/4;
    c8.start4[3] = c8.start4[2] + KEY_DIM*HID/4;
    c8.start4[4] = c8.start4[3] + VAL_DIM*HID/4;
    c8.start4[5] = c8.start4[4] + VAL_DIM*HID/4;
    c8.start4[6] = c8.start4[5] + NH*HID/4;
    c8.start4[7] = c8.start4[6] + NH*HID/4;
    c8.start4[8] = c8.start4[7] + (QW - OFF_A - 12)*HID/4;   // 116-row zero pad
    cast_multi<<<dim3(2048), blk, 0, stream>>>(c8, xb);

    // fused q|k|v|gate|a|b projection: barrier-free wave-private pipeline,
    // 64x64 tiles, 4672 one-wave blocks (%8==0), XCD-chunked
    gemm_qkvg<<<dim3((ROWS/64) * (QW/64)), dim3(64), 0, stream>>>(
        xb, Wqb, qkvg, ab32, ROWS, QW, HID);

    cumsum_pack<<<dim3(NG), dim3(64), 0, stream>>>(ab32, A_log, dtb, cinc, cexc, barr);
    prep_norm<<<dim3(ROWS), dim3(384), 0, stream>>>(qkvg, decay, Dp, barr, qb, kb, bvb);
    a_mat<<<dim3(NG*36), blk, 0, stream>>>(kb, cinc, cexc, barr, Ab, Minvb);  // fused minv
    usolve<<<dim3(NG*16), blk, 0, stream>>>(Ab, Minvb, bvb, Utb);
    o_kern<<<dim3(NG*16), blk, 0, stream>>>(qb, kb, Utb, cinc, qkvg);
    epilogue<<<dim3(ROWS), dim3(384), 0, stream>>>(qkvg, onw, ob);

    // output projection: split-K=4, 1024 blocks, bf16 partials + fp32 reduce
    cast_f32_bf16<<<cblocks((size_t)HID*VAL_DIM), blk, 0, stream>>>(Wo, Wob, HID*VAL_DIM/4);
    gemm_nt_splitk4<<<dim3(4 * (HID/128) * (ROWS/128)), blk, 0, stream>>>(
        ob, Wob, P0, P1, P2, P3, ROWS, HID, VAL_DIM);
    add4_bf16<<<dim3(2048), blk, 0, stream>>>(out, P0, P1, P2, P3, ROWS*HID/4);
}

// Round 23
// 360.930 us; speedup vs baseline: 1.1702x; 1.1702x over previous
//
#include <hip/hip_runtime.h>
#include <hip/hip_bf16.h>
#include <math.h>

#define BB 4
#define TT 512
#define HID 2048
#define NH 6
#define DK 256
#define DV 512
#define ROWS (BB*TT)          /* 2048 */
#define KEY_DIM (NH*DK)       /* 1536 */
#define VAL_DIM (NH*DV)       /* 3072 */
#define NG (BB*NH)            /* 24 groups */
#define NC 8                  /* chunks */
#define CL 64                 /* chunk length */
#define QW 9344               /* fused row stride: q|k|v|gate|a|b|pad */
#define OFF_K 1536
#define OFF_V 3072
#define OFF_G 6144
#define OFF_A 9216

typedef __bf16 bf16x8 __attribute__((ext_vector_type(8)));
typedef float  f32x4  __attribute__((ext_vector_type(4)));

__device__ __forceinline__ unsigned short f2bf(float f) {
    unsigned int u = __float_as_uint(f);
    u = (u + 0x7FFFu + ((u >> 16) & 1u)) >> 16;
    return (unsigned short)u;
}
__device__ __forceinline__ float b2f(unsigned short u) {
    return __uint_as_float(((unsigned int)u) << 16);
}

// ---------------------------------------------------------------------------
// fp32 -> bf16 cast (RNE), vectorized. Single-source variant (Wo).
// ---------------------------------------------------------------------------
__global__ __launch_bounds__(256) void cast_f32_bf16(
    const float* __restrict__ src, unsigned short* __restrict__ dst, int n4)
{
    int stride = gridDim.x * 256;
    for (int i = blockIdx.x * 256 + threadIdx.x; i < n4; i += stride) {
        float4 v = ((const float4*)src)[i];
        ushort4 o;
        o.x = f2bf(v.x); o.y = f2bf(v.y); o.z = f2bf(v.z); o.w = f2bf(v.w);
        ((ushort4*)dst)[i] = o;
    }
}

// ---------------------------------------------------------------------------
// Multi-source fp32 -> bf16 cast: 8 sources (nullptr -> zero fill), one
// contiguous destination. Builds x | Wq | Wk | Wv | Wg | Wa | Wb | 0-pad.
// ---------------------------------------------------------------------------
struct Cast8 {
    const float* src[8];
    int start4[9];           // cumulative float4 offsets into dst
};
__global__ __launch_bounds__(256) void cast_multi(Cast8 c, unsigned short* __restrict__ dst)
{
    const int total = c.start4[8];
    int stride = gridDim.x * 256;
    for (int i = blockIdx.x * 256 + threadIdx.x; i < total; i += stride) {
        int s = 0;
        while (i >= c.start4[s + 1]) ++s;
        float4 v = make_float4(0.f, 0.f, 0.f, 0.f);
        if (c.src[s]) v = ((const float4*)c.src[s])[i - c.start4[s]];
        ushort4 o;
        o.x = f2bf(v.x); o.y = f2bf(v.y); o.z = f2bf(v.z); o.w = f2bf(v.w);
        ((ushort4*)dst)[i] = o;
    }
}

// ---------------------------------------------------------------------------
// out = p0+p1+p2+p3 (bf16 partials, fp32 sum/store; deterministic order).
// ---------------------------------------------------------------------------
__global__ __launch_bounds__(256) void add4_bf16(
    float* __restrict__ out, const unsigned short* __restrict__ p0,
    const unsigned short* __restrict__ p1, const unsigned short* __restrict__ p2,
    const unsigned short* __restrict__ p3, int n4)
{
    int stride = gridDim.x * 256;
    for (int i = blockIdx.x * 256 + threadIdx.x; i < n4; i += stride) {
        ushort4 a = ((const ushort4*)p0)[i];
        ushort4 b = ((const ushort4*)p1)[i];
        ushort4 c = ((const ushort4*)p2)[i];
        ushort4 d = ((const ushort4*)p3)[i];
        float4 o;
        o.x = ((b2f(a.x) + b2f(b.x)) + b2f(c.x)) + b2f(d.x);
        o.y = ((b2f(a.y) + b2f(b.y)) + b2f(c.y)) + b2f(d.y);
        o.z = ((b2f(a.z) + b2f(b.z)) + b2f(c.z)) + b2f(d.z);
        o.w = ((b2f(a.w) + b2f(b.w)) + b2f(c.w)) + b2f(d.w);
        ((float4*)out)[i] = o;
    }
}

// ---------------------------------------------------------------------------
// QKVG fused-projection GEMM: C bf16 [M][N], a/b cols (OFF_A..OFF_A+11)
// ALSO stored fp32 to ab32[row][12] (decay exponents need full precision).
// 128x128 tile, BK=32, 2-phase dbuf, XCD-chunked 1D grid (%8==0).
// [R16/R21 measured-best config. FOUR schedule variants regressed vs this:
// R15 regcap (spills), R17 256^2 ring (1 blk/CU + 2 rounds), R18 k-outer
// (uncoalesced staging), R22 wave-private 64^2 (2x FETCH, low occupancy).
// GEMM axis closed — do not touch.]
// ---------------------------------------------------------------------------
__global__ __launch_bounds__(256) void gemm_qkvg(
    const unsigned short* __restrict__ A, const unsigned short* __restrict__ B,
    unsigned short* __restrict__ C, float* __restrict__ ab32, int M, int N, int K)
{
    __shared__ __align__(16) unsigned short As[2][128 * 32];
    __shared__ __align__(16) unsigned short Bs[2][128 * 32];
    const int tid  = threadIdx.x;
    const int lane = tid & 63;
    const int wave = tid >> 6;
    const int per  = gridDim.x >> 3;
    const int lg   = (blockIdx.x & 7) * per + (blockIdx.x >> 3);
    const int bm = (lg & 15) * 128;      // by fast-varying (M = 2048)
    const int bn = (lg >> 4) * 128;      // B-tile, contiguous per XCD
    const int wr = (wave >> 1) * 64;
    const int wc = (wave & 1) * 64;
    const int fr = lane & 15;
    const int kg = lane >> 4;

    f32x4 acc[4][4] = {};

#define GSTAGE(buf, k0) do { \
    _Pragma("unroll") \
    for (int s_ = 0; s_ < 2; ++s_) { \
        int e_  = s_ * 256 + tid; \
        int r_  = e_ >> 2; \
        int c8_ = (e_ & 3) * 8; \
        const unsigned short* ga_ = A + (size_t)(bm + r_) * K + (k0) + c8_; \
        const unsigned short* gb_ = B + (size_t)(bn + r_) * K + (k0) + c8_; \
        unsigned short* la_ = As[buf] + (size_t)(s_ * 256 + wave * 64) * 8; \
        unsigned short* lb_ = Bs[buf] + (size_t)(s_ * 256 + wave * 64) * 8; \
        __builtin_amdgcn_global_load_lds( \
            (const __attribute__((address_space(1))) void*)ga_, \
            (__attribute__((address_space(3))) void*)la_, 16, 0, 0); \
        __builtin_amdgcn_global_load_lds( \
            (const __attribute__((address_space(1))) void*)gb_, \
            (__attribute__((address_space(3))) void*)lb_, 16, 0, 0); \
    } \
} while (0)

    GSTAGE(0, 0);
    __syncthreads();

    int cur = 0;
    for (int k0 = 0; k0 < K; k0 += 32) {
        if (k0 + 32 < K) GSTAGE(cur ^ 1, k0 + 32);

        bf16x8 a[4], b[4];
        #pragma unroll
        for (int f = 0; f < 4; ++f) {
            a[f] = *(const bf16x8*)&As[cur][(wr + f * 16 + fr) * 32 + kg * 8];
            b[f] = *(const bf16x8*)&Bs[cur][(wc + f * 16 + fr) * 32 + kg * 8];
        }
        #pragma unroll
        for (int fm = 0; fm < 4; ++fm)
            #pragma unroll
            for (int fn = 0; fn < 4; ++fn)
                acc[fm][fn] = __builtin_amdgcn_mfma_f32_16x16x32_bf16(
                    a[fm], b[fn], acc[fm][fn], 0, 0, 0);

        __syncthreads();
        cur ^= 1;
    }
#undef GSTAGE

    #pragma unroll
    for (int fm = 0; fm < 4; ++fm)
        #pragma unroll
        for (int fn = 0; fn < 4; ++fn) {
            int col = bn + wc + fn * 16 + fr;
            bool isab = (col >= OFF_A) && (col < OFF_A + 12);
            #pragma unroll
            for (int i = 0; i < 4; ++i) {
                int row = bm + wr + fm * 16 + kg * 4 + i;
                float v = acc[fm][fn][i];
                C[(size_t)row * N + col] = f2bf(v);
                if (isab) ab32[(size_t)row * 12 + (col - OFF_A)] = v;
            }
        }
}

// ---------------------------------------------------------------------------
// Split-K=4 GEMM for the grid-starved Wo projection (M=2048,N=2048,K=3072):
// ONE dispatch, 1024 blocks. All four K-quarters store bf16 partials
// (P0..P3); add4_bf16 sums them in fp32 (deterministic).
// ---------------------------------------------------------------------------
__global__ __launch_bounds__(256) void gemm_nt_splitk4(
    const unsigned short* __restrict__ A, const unsigned short* __restrict__ B,
    unsigned short* __restrict__ C0, unsigned short* __restrict__ C1,
    unsigned short* __restrict__ C2, unsigned short* __restrict__ C3,
    int M, int N, int K)
{
    __shared__ __align__(16) unsigned short As[2][128 * 32];
    __shared__ __align__(16) unsigned short Bs[2][128 * 32];
    const int tid  = threadIdx.x;
    const int lane = tid & 63;
    const int wave = tid >> 6;
    const int per  = gridDim.x >> 3;
    const int lg   = (blockIdx.x & 7) * per + (blockIdx.x >> 3);
    const int kh   = lg & 3;
    const int bmn  = lg >> 2;
    const int bm = (bmn & 15) * 128;
    const int bn = (bmn >> 4) * 128;
    const int wr = (wave >> 1) * 64;
    const int wc = (wave & 1) * 64;
    const int fr = lane & 15;
    const int kg = lane >> 4;
    const int Kq = K >> 2;               // 768 -> 24 steps
    const int kbase = kh * Kq;

    f32x4 acc[4][4] = {};

#define GSTAGE(buf, k0) do { \
    _Pragma("unroll") \
    for (int s_ = 0; s_ < 2; ++s_) { \
        int e_  = s_ * 256 + tid; \
        int r_  = e_ >> 2; \
        int c8_ = (e_ & 3) * 8; \
        const unsigned short* ga_ = A + (size_t)(bm + r_) * K + (k0) + c8_; \
        const unsigned short* gb_ = B + (size_t)(bn + r_) * K + (k0) + c8_; \
        unsigned short* la_ = As[buf] + (size_t)(s_ * 256 + wave * 64) * 8; \
        unsigned short* lb_ = Bs[buf] + (size_t)(s_ * 256 + wave * 64) * 8; \
        __builtin_amdgcn_global_load_lds( \
            (const __attribute__((address_space(1))) void*)ga_, \
            (__attribute__((address_space(3))) void*)la_, 16, 0, 0); \
        __builtin_amdgcn_global_load_lds( \
            (const __attribute__((address_space(1))) void*)gb_, \
            (__attribute__((address_space(3))) void*)lb_, 16, 0, 0); \
    } \
} while (0)

    GSTAGE(0, kbase);
    __syncthreads();

    int cur = 0;
    for (int k0 = kbase; k0 < kbase + Kq; k0 += 32) {
        if (k0 + 32 < kbase + Kq) GSTAGE(cur ^ 1, k0 + 32);

        bf16x8 a[4], b[4];
        #pragma unroll
        for (int f = 0; f < 4; ++f) {
            a[f] = *(const bf16x8*)&As[cur][(wr + f * 16 + fr) * 32 + kg * 8];
            b[f] = *(const bf16x8*)&Bs[cur][(wc + f * 16 + fr) * 32 + kg * 8];
        }
        #pragma unroll
        for (int fm = 0; fm < 4; ++fm)
            #pragma unroll
            for (int fn = 0; fn < 4; ++fn)
                acc[fm][fn] = __builtin_amdgcn_mfma_f32_16x16x32_bf16(
                    a[fm], b[fn], acc[fm][fn], 0, 0, 0);

        __syncthreads();
        cur ^= 1;
    }
#undef GSTAGE

    unsigned short* C = (kh == 0) ? C0 : (kh == 1) ? C1 : (kh == 2) ? C2 : C3;
    #pragma unroll
    for (int fm = 0; fm < 4; ++fm)
        #pragma unroll
        for (int fn = 0; fn < 4; ++fn) {
            int col = bn + wc + fn * 16 + fr;
            #pragma unroll
            for (int i = 0; i < 4; ++i) {
                int row = bm + wr + fm * 16 + kg * 4 + i;
                C[(size_t)row * N + col] = f2bf(acc[fm][fn][i]);
            }
        }
}

// ---------------------------------------------------------------------------
// Per-group: a/b (fp32 side-store) -> g, beta; cumulative log-decay scan;
// writes cinc/cexc/barr. 24 blocks x 64 threads.
// ---------------------------------------------------------------------------
__global__ __launch_bounds__(64) void cumsum_pack(
    const float* __restrict__ ab32,
    const float* __restrict__ A_log, const float* __restrict__ dt_bias,
    float* __restrict__ cinc, float* __restrict__ cexc, float* __restrict__ barr)
{
    const int g = blockIdx.x;
    const int b = g / NH, h = g % NH;
    const int lane = threadIdx.x;
    const float nA = -expf(A_log[h]);
    const float db = dt_bias[h];
    float carry = 0.f;
    for (int c0 = 0; c0 < TT; c0 += 64) {
        int t = c0 + lane;
        size_t rbase = (size_t)(b*TT + t) * 12;
        float a  = ab32[rbase + h] + db;
        float sp = (a > 20.f) ? a : log1pf(expf(a));
        float gv = nA * sp;
        float bp = ab32[rbase + 6 + h];
        float x = gv;
        #pragma unroll
        for (int off = 1; off < 64; off <<= 1) {
            float n = __shfl_up(x, off);
            if (lane >= off) x += n;
        }
        float inc = carry + x;
        cinc[(size_t)g*TT + t] = inc;
        cexc[(size_t)g*TT + t] = inc - gv;
        barr[(size_t)g*TT + t] = 1.f / (1.f + expf(-bp));
        carry = __shfl(inc, 63);
    }
}

// ---------------------------------------------------------------------------
// Pointwise prep v2: barrier-free. 384 threads = 6 waves; wave h owns head h.
// ---------------------------------------------------------------------------
__global__ __launch_bounds__(384) void prep_norm(
    const unsigned short* __restrict__ qkvg,
    const float* __restrict__ decay, const float* __restrict__ D,
    const float* __restrict__ barr,
    unsigned short* __restrict__ qb, unsigned short* __restrict__ kb,
    unsigned short* __restrict__ bvb)
{
    const int row  = blockIdx.x;
    const int b    = row >> 9, t = row & 511;
    const int tid  = threadIdx.x;
    const int h    = tid >> 6;       // wave = head
    const int lane = tid & 63;

    size_t base = (size_t)row * QW + h * DK + lane * 4;
    ushort4 qu = *(const ushort4*)&qkvg[base];
    ushort4 ku = *(const ushort4*)&qkvg[base + OFF_K];
    float qv[4] = {b2f(qu.x), b2f(qu.y), b2f(qu.z), b2f(qu.w)};
    float kv[4] = {b2f(ku.x), b2f(ku.y), b2f(ku.z), b2f(ku.w)};
    const float coef = D[h] * (1.f / (1.f + expf(-decay[h])));
    float qc[4], kl[4];
    float sq = 0.f, sk = 0.f;
    #pragma unroll
    for (int i = 0; i < 4; ++i) {
        float ksil = kv[i] / (1.f + expf(-kv[i]));
        float qsil = qv[i] / (1.f + expf(-qv[i]));
        qc[i] = qsil - coef * ksil;
        kl[i] = ksil;
        sq += qc[i] * qc[i];
        sk += ksil * ksil;
    }
    #pragma unroll
    for (int off = 32; off >= 1; off >>= 1) {
        sq += __shfl_xor(sq, off);
        sk += __shfl_xor(sk, off);
    }
    float qinv = 0.0625f / fmaxf(sqrtf(sq), 1e-12f);
    float kinv = 1.f     / fmaxf(sqrtf(sk), 1e-12f);
    size_t gidx = (((size_t)(b*NH + h)) * TT + t) * DK + lane * 4;
    ushort4 qo, ko;
    qo.x = f2bf(qc[0]*qinv); qo.y = f2bf(qc[1]*qinv);
    qo.z = f2bf(qc[2]*qinv); qo.w = f2bf(qc[3]*qinv);
    ko.x = f2bf(kl[0]*kinv); ko.y = f2bf(kl[1]*kinv);
    ko.z = f2bf(kl[2]*kinv); ko.w = f2bf(kl[3]*kinv);
    *(ushort4*)&qb[gidx] = qo;
    *(ushort4*)&kb[gidx] = ko;

    const int jj0 = tid * 8;
    const int h2  = jj0 >> 9;
    const int dv  = jj0 & 511;
    float bt = barr[((size_t)(b*NH + h2)) * TT + t];
    const unsigned short* vp = &qkvg[(size_t)row * QW + OFF_V + jj0];
    unsigned short* bp = &bvb[(((size_t)(b*NH + h2)) * TT + t) * DV + dv];
    ushort4 v0 = *(const ushort4*)vp;
    ushort4 v1 = *(const ushort4*)(vp + 4);
    unsigned short vi[8] = {v0.x, v0.y, v0.z, v0.w, v1.x, v1.y, v1.z, v1.w};
    ushort4 o0, o1;
    unsigned short vo[8];
    #pragma unroll
    for (int i = 0; i < 8; ++i) {
        float xv = b2f(vi[i]);
        float sv = xv / (1.f + expf(-xv));
        vo[i] = f2bf(bt * sv);
    }
    o0.x = vo[0]; o0.y = vo[1]; o0.z = vo[2]; o0.w = vo[3];
    o1.x = vo[4]; o1.y = vo[5]; o1.z = vo[6]; o1.w = vo[7];
    *(ushort4*)bp       = o0;
    *(ushort4*)(bp + 4) = o1;
}

// ---------------------------------------------------------------------------
// A-matrix tiles: A[i,j] = beta_i * exp(cexc_i - cinc_j) * (k_i . k_j), j<i.
// Diagonal blocks (l==m) ALSO compute the unit-lower-triangular inverse of
// (I + A_mm) in-kernel (fused minv).
// ---------------------------------------------------------------------------
__global__ __launch_bounds__(256) void a_mat(
    const unsigned short* __restrict__ kb, const float* __restrict__ cinc,
    const float* __restrict__ cexc, const float* __restrict__ barr,
    unsigned short* __restrict__ Ab, unsigned short* __restrict__ Minvb)
{
    __shared__ __align__(16) unsigned short Asub[64][72];
    __shared__ __align__(16) float Xt[64][68];

    const int blk = blockIdx.x;
    const int g = blk / 36;
    int p = blk % 36, m = 0, acc0 = 0;
    while (p >= acc0 + m + 1) { acc0 += m + 1; ++m; }
    const int l = p - acc0;
    const int tid = threadIdx.x, lane = tid & 63, w = tid >> 6;
    const int fr = lane & 15, kg = lane >> 4;
    const unsigned short* Km = kb + (((size_t)g*TT) + m*CL) * DK;
    const unsigned short* Kl = kb + (((size_t)g*TT) + l*CL) * DK;
    f32x4 acc[4] = {};
    #pragma unroll
    for (int ks = 0; ks < 8; ++ks) {
        bf16x8 a = *(const bf16x8*)(Km + (size_t)(w*16 + fr)*DK + ks*32 + kg*8);
        bf16x8 bb[4];
        #pragma unroll
        for (int fn = 0; fn < 4; ++fn)
            bb[fn] = *(const bf16x8*)(Kl + (size_t)(fn*16 + fr)*DK + ks*32 + kg*8);
        #pragma unroll
        for (int fn = 0; fn < 4; ++fn)
            acc[fn] = __builtin_amdgcn_mfma_f32_16x16x32_bf16(a, bb[fn], acc[fn], 0, 0, 0);
    }
    const float* ci = cinc + (size_t)g*TT;
    const float* ce = cexc + (size_t)g*TT;
    const float* bb2 = barr + (size_t)g*TT;
    const bool diag = (l == m);
    #pragma unroll
    for (int fn = 0; fn < 4; ++fn) {
        int jl = fn*16 + fr;
        int tj = l*CL + jl;
        float cj = ci[tj];
        #pragma unroll
        for (int r = 0; r < 4; ++r) {
            int il = w*16 + kg*4 + r;
            int ti = m*CL + il;
            float val = 0.f;
            if (tj < ti) val = bb2[ti] * __expf(ce[ti] - cj) * acc[fn][r];
            unsigned short vb = f2bf(val);
            Ab[((size_t)g*TT + ti)*TT + tj] = vb;
            if (diag) Asub[il][jl] = vb;
        }
    }

    if (diag) {
        __syncthreads();                 // Asub staged by all 4 waves
        if (tid < 64) {                  // wave 0: wave-synchronous inverse
            const int col = tid;
            #pragma unroll
            for (int t4 = 0; t4 < 17; ++t4)
                *(float4*)&Xt[col][t4*4] = make_float4(0.f, 0.f, 0.f, 0.f);
            Xt[col][col] = 1.f;
            #pragma unroll 1
            for (int i = 1; i < 64; ++i) {
                const int nch = (i + 7) >> 3;
                float s = 0.f;
                #pragma unroll 1
                for (int c8 = 0; c8 < nch; ++c8) {
                    ushort4 a0 = *(const ushort4*)&Asub[i][c8*8];
                    ushort4 a1 = *(const ushort4*)&Asub[i][c8*8 + 4];
                    float4  x0 = *(const float4*)&Xt[col][c8*8];
                    float4  x1 = *(const float4*)&Xt[col][c8*8 + 4];
                    s += b2f(a0.x)*x0.x; s += b2f(a0.y)*x0.y;
                    s += b2f(a0.z)*x0.z; s += b2f(a0.w)*x0.w;
                    s += b2f(a1.x)*x1.x; s += b2f(a1.y)*x1.y;
                    s += b2f(a1.z)*x1.z; s += b2f(a1.w)*x1.w;
                }
                if (col < i) Xt[col][i] = -s;
            }
            unsigned short* outp = Minvb + (size_t)(g*8 + m) * 4096;
            #pragma unroll 4
            for (int r = 0; r < 64; ++r)
                outp[(size_t)r*64 + col] = f2bf(Xt[col][r]);
        }
    }
}

// ---------------------------------------------------------------------------
// U-solve v3: (I+A) U = beta*V, block forward substitution over 8 chunks.
// grid = 24 groups x 16 v-slices(32) = 384 blocks. Utb[g][v][t] bf16.
// Block's whole U slice mirrored in LDS (Uls[32][520]); all chunk-to-chunk
// U reads come from LDS (no global RAW round-trips). Bit-identical.
// ---------------------------------------------------------------------------
__global__ __launch_bounds__(256) void usolve(
    const unsigned short* __restrict__ Ab, const unsigned short* __restrict__ Minvb,
    const unsigned short* __restrict__ bvb, unsigned short* __restrict__ Utb)
{
    const int blk = blockIdx.x;
    const int g = blk >> 4, vs = blk & 15;
    const int tid = threadIdx.x, lane = tid & 63, w = tid >> 6;
    const int fr = lane & 15, kg = lane >> 4;
    __shared__ __align__(16) unsigned short TACC[2][32][40];
    __shared__ __align__(16) unsigned short Uls[32][520];   // [v][t], pad->2-way

    for (int m = 0; m < NC; ++m) {
        f32x4 acc[2] = {};
        for (int l = 0; l < m; ++l) {
            const unsigned short* Aml = Ab + (((size_t)g*TT) + m*CL)*TT + l*CL;
            #pragma unroll
            for (int ks = 0; ks < 2; ++ks) {
                bf16x8 a = *(const bf16x8*)(Aml + (size_t)(w*16 + fr)*TT + ks*32 + kg*8);
                bf16x8 bb[2];
                #pragma unroll
                for (int fn = 0; fn < 2; ++fn)
                    bb[fn] = *(const bf16x8*)&Uls[fn*16 + fr][l*CL + ks*32 + kg*8];
                #pragma unroll
                for (int fn = 0; fn < 2; ++fn)
                    acc[fn] = __builtin_amdgcn_mfma_f32_16x16x32_bf16(a, bb[fn], acc[fn], 0, 0, 0);
            }
        }
        __syncthreads();
        const unsigned short* bvg = bvb + (((size_t)g*TT) + m*CL)*DV + vs*32;
        #pragma unroll
        for (int fn = 0; fn < 2; ++fn) {
            int v = fn*16 + fr;
            #pragma unroll
            for (int r = 0; r < 4; ++r) {
                int i = w*16 + kg*4 + r;
                float rhs = b2f(bvg[(size_t)i*DV + v]) - acc[fn][r];
                TACC[i >> 5][v][i & 31] = f2bf(rhs);
            }
        }
        __syncthreads();
        const unsigned short* Mi = Minvb + (size_t)(g*8 + m) * 4096;
        f32x4 acc2[2] = {};
        #pragma unroll
        for (int ks = 0; ks < 2; ++ks) {
            bf16x8 a = *(const bf16x8*)(Mi + (size_t)(w*16 + fr)*64 + ks*32 + kg*8);
            bf16x8 bb[2];
            #pragma unroll
            for (int fn = 0; fn < 2; ++fn)
                bb[fn] = *(const bf16x8*)&TACC[ks][fn*16 + fr][kg*8];
            #pragma unroll
            for (int fn = 0; fn < 2; ++fn)
                acc2[fn] = __builtin_amdgcn_mfma_f32_16x16x32_bf16(a, bb[fn], acc2[fn], 0, 0, 0);
        }
        unsigned short* Um = Utb + (((size_t)g*TT) + vs*32)*TT + m*CL;
        #pragma unroll
        for (int fn = 0; fn < 2; ++fn) {
            int v = fn*16 + fr;
            #pragma unroll
            for (int r = 0; r < 4; ++r) {
                int i = w*16 + kg*4 + r;
                unsigned short uv = f2bf(acc2[fn][r]);
                Um[(size_t)v*TT + i] = uv;          // for o_kern
                Uls[v][m*CL + i]    = uv;           // for later chunks (LDS)
            }
        }
        __syncthreads();   // LDS U-chunk visible before next chunk reads it
    }
}

// ---------------------------------------------------------------------------
// Output: o_i = sum_{j<=i} exp(c_i - c_j)*(q_i . k_j) * u_j.
// Block = (g, m-pair {p, 7-p}, v-quarter 128). 9 balanced l-iters per block.
// K/U tiles async-staged into double-buffered swizzled LDS; Q in registers.
// Writes o bf16 into the fused qkvg buffer's (dead) v columns @3072.
// ---------------------------------------------------------------------------
__global__ __launch_bounds__(256) void o_kern(
    const unsigned short* __restrict__ qb, const unsigned short* __restrict__ kb,
    const unsigned short* __restrict__ Utb, const float* __restrict__ cinc,
    unsigned short* __restrict__ qkvg)
{
    __shared__ __align__(16) unsigned short Kls[2][64*256];   // 64 KB
    __shared__ __align__(16) unsigned short Uls[2][128*64];   // 32 KB
    __shared__ __align__(16) unsigned short Ps[2][64][40];    // 10 KB
    __shared__ float cgl[TT];                                 // 2 KB

    const int blk = blockIdx.x;
    const int g  = blk >> 4;
    const int rm = blk & 15;
    const int pr = rm >> 2;
    const int vq = rm & 3;
    const int b = g / NH, h = g % NH;
    const int tid = threadIdx.x, lane = tid & 63, w = tid >> 6;
    const int fr = lane & 15, kg = lane >> 4;

    const unsigned short* kgrp = kb  + (size_t)g*TT*DK;
    const unsigned short* ugrp = Utb + ((size_t)g*TT + vq*128)*TT;

#define STAGE_K(buf, l) do { \
    _Pragma("unroll") \
    for (int s_ = 0; s_ < 8; ++s_) { \
        int slot_ = s_*256 + tid; \
        int gc_ = slot_ ^ ((slot_ >> 5) & 7); \
        const unsigned short* ga_ = kgrp + (size_t)(l)*CL*DK + gc_*8; \
        __builtin_amdgcn_global_load_lds( \
            (const __attribute__((address_space(1))) void*)ga_, \
            (__attribute__((address_space(3))) void*)&Kls[buf][slot_*8], 16, 0, 0); \
    } \
} while (0)

#define STAGE_U(buf, l) do { \
    _Pragma("unroll") \
    for (int s_ = 0; s_ < 4; ++s_) { \
        int slot_ = s_*256 + tid; \
        int gc_ = slot_ ^ ((slot_ >> 3) & 7); \
        const unsigned short* ga_ = ugrp + (size_t)(gc_ >> 3)*TT + (l)*CL + (gc_ & 7)*8; \
        __builtin_amdgcn_global_load_lds( \
            (const __attribute__((address_space(1))) void*)ga_, \
            (__attribute__((address_space(3))) void*)&Uls[buf][slot_*8], 16, 0, 0); \
    } \
} while (0)

    cgl[tid]       = cinc[(size_t)g*TT + tid];
    cgl[tid + 256] = cinc[(size_t)g*TT + tid + 256];
    STAGE_K(0, 0);
    STAGE_U(0, 0);
    __syncthreads();

    int cur = 0;
    #pragma unroll 1
    for (int mi_idx = 0; mi_idx < 2; ++mi_idx) {
        const int mi = mi_idx ? (7 - pr) : pr;
        const unsigned short* Qm = qb + (((size_t)g*TT) + mi*CL) * DK + (size_t)(w*16 + fr)*DK;
        bf16x8 qf[8];
        #pragma unroll
        for (int ks = 0; ks < 8; ++ks) qf[ks] = *(const bf16x8*)(Qm + ks*32 + kg*8);

        f32x4 acc[8] = {};
        #pragma unroll 1
        for (int l = 0; l <= mi; ++l) {
            if (l < mi)            { STAGE_K(cur^1, l+1); STAGE_U(cur^1, l+1); }
            else if (mi_idx == 0)  { STAGE_K(cur^1, 0);   STAGE_U(cur^1, 0);   }

            f32x4 sacc[4] = {};
            #pragma unroll
            for (int ks = 0; ks < 8; ++ks) {
                bf16x8 bbf[4];
                #pragma unroll
                for (int fn = 0; fn < 4; ++fn) {
                    int row = fn*16 + fr;
                    int slot = (row*32 + ks*4 + kg) ^ (row & 7);
                    bbf[fn] = *(const bf16x8*)&Kls[cur][slot*8];
                }
                #pragma unroll
                for (int fn = 0; fn < 4; ++fn)
                    sacc[fn] = __builtin_amdgcn_mfma_f32_16x16x32_bf16(qf[ks], bbf[fn], sacc[fn], 0, 0, 0);
            }
            __syncthreads();

            #pragma unroll
            for (int fn = 0; fn < 4; ++fn) {
                int jl = fn*16 + fr;
                float cjv = cgl[l*CL + jl];
                #pragma unroll
                for (int r = 0; r < 4; ++r) {
                    int il = w*16 + kg*4 + r;
                    float val = ((l*CL + jl) <= (mi*CL + il))
                              ? sacc[fn][r] * __expf(cgl[mi*CL + il] - cjv) : 0.f;
                    Ps[jl >> 5][il][jl & 31] = f2bf(val);
                }
            }
            __syncthreads();

            #pragma unroll
            for (int ks = 0; ks < 2; ++ks) {
                bf16x8 a = *(const bf16x8*)&Ps[ks][w*16 + fr][kg*8];
                bf16x8 bbf[8];
                #pragma unroll
                for (int fn = 0; fn < 8; ++fn) {
                    int vrow = fn*16 + fr;
                    int slot = (vrow*8 + ks*4 + kg) ^ (vrow & 7);
                    bbf[fn] = *(const bf16x8*)&Uls[cur][slot*8];
                }
                #pragma unroll
                for (int fn = 0; fn < 8; ++fn)
                    acc[fn] = __builtin_amdgcn_mfma_f32_16x16x32_bf16(a, bbf[fn], acc[fn], 0, 0, 0);
            }
            __syncthreads();
            cur ^= 1;
        }

        // store o (bf16) into fused buffer (dead v columns): [row][QW]@3072
        unsigned short* ob = qkvg + ((size_t)(b*TT + mi*CL)) * QW + OFF_V + h*DV + vq*128;
        #pragma unroll
        for (int fn = 0; fn < 8; ++fn) {
            int v = fn*16 + fr;
            #pragma unroll
            for (int r = 0; r < 4; ++r) {
                int il = w*16 + kg*4 + r;
                ob[(size_t)il*QW + v] = f2bf(acc[fn][r]);
            }
        }
    }
#undef STAGE_K
#undef STAGE_U
}

// ---------------------------------------------------------------------------
// Gated RMSNorm epilogue v2: barrier-free. 384 threads = 6 waves; wave h owns
// head h: 8 elems/lane, wave-local shfl reduction, 16B loads/stores.
// ---------------------------------------------------------------------------
__global__ __launch_bounds__(384) void epilogue(
    const unsigned short* __restrict__ qkvg, const float* __restrict__ wnorm,
    unsigned short* __restrict__ ob)
{
    const int row  = blockIdx.x;
    const int tid  = threadIdx.x;
    const int h    = tid >> 6;
    const int lane = tid & 63;

    size_t base = (size_t)row * QW + OFF_V + h * DV + lane * 8;
    ushort4 a0 = *(const ushort4*)&qkvg[base];
    ushort4 a1 = *(const ushort4*)&qkvg[base + 4];
    unsigned short oi[8] = {a0.x, a0.y, a0.z, a0.w, a1.x, a1.y, a1.z, a1.w};
    float ov[8];
    float ss = 0.f;
    #pragma unroll
    for (int i = 0; i < 8; ++i) { ov[i] = b2f(oi[i]); ss += ov[i]*ov[i]; }
    #pragma unroll
    for (int off = 32; off >= 1; off >>= 1) ss += __shfl_xor(ss, off);
    float irms = rsqrtf(ss * (1.f / DV) + 1e-6f);

    size_t gbase = (size_t)row * QW + OFF_G + h * DV + lane * 8;
    ushort4 g0 = *(const ushort4*)&qkvg[gbase];
    ushort4 g1 = *(const ushort4*)&qkvg[gbase + 4];
    unsigned short gi[8] = {g0.x, g0.y, g0.z, g0.w, g1.x, g1.y, g1.z, g1.w};

    unsigned short vo[8];
    #pragma unroll
    for (int i = 0; i < 8; ++i) {
        float gv = b2f(gi[i]);
        float wv = wnorm[lane*8 + i];
        vo[i] = f2bf(ov[i] * irms * wv * (1.f / (1.f + expf(-gv))));
    }
    size_t obase = (size_t)row * VAL_DIM + h * DV + lane * 8;
    ushort4 w0, w1;
    w0.x = vo[0]; w0.y = vo[1]; w0.z = vo[2]; w0.w = vo[3];
    w1.x = vo[4]; w1.y = vo[5]; w1.z = vo[6]; w1.w = vo[7];
    *(ushort4*)&ob[obase]     = w0;
    *(ushort4*)&ob[obase + 4] = w1;
}

// ---------------------------------------------------------------------------
extern "C" void kernel_launch(void* const* d_in, const int* in_sizes, int n_in,
                              void* d_out, int out_size, void* d_ws, size_t ws_size,
                              hipStream_t stream)
{
    const float* x     = (const float*)d_in[0];
    const float* Wq    = (const float*)d_in[1];
    const float* Wk    = (const float*)d_in[2];
    const float* Wv    = (const float*)d_in[3];
    const float* Wa    = (const float*)d_in[4];
    const float* Wb    = (const float*)d_in[5];
    const float* decay = (const float*)d_in[6];
    const float* Dp    = (const float*)d_in[7];
    const float* A_log = (const float*)d_in[8];
    const float* dtb   = (const float*)d_in[9];
    const float* Wg    = (const float*)d_in[10];
    const float* Wo    = (const float*)d_in[11];
    const float* onw   = (const float*)d_in[12];
    float* out = (float*)d_out;

    unsigned short* qkvg = (unsigned short*)d_ws;            // ROWS*QW bf16 (38.3 MB)
    float* ab32 = (float*)(qkvg + (size_t)ROWS * QW);        // ROWS*12 fp32 (a|b cols)
    float* cinc = ab32 + (size_t)ROWS * 12;                  // NG*TT
    float* cexc = cinc + (size_t)NG * TT;
    float* barr = cexc + (size_t)NG * TT;
    unsigned short* bf = (unsigned short*)(barr + (size_t)NG * TT);

    // phase 1 (projections): weight block is one contiguous [9344][2048]
    // bf16 matrix (order q,k,v,g,a,b,zero-pad).
    unsigned short* xb  = bf;                                   // ROWS*HID
    unsigned short* Wqb = xb  + (size_t)ROWS * HID;
    // phase R (chunked recurrence) — aliases phase 1 (dead by then)
    unsigned short* qb    = bf;                                 // NG*TT*DK
    unsigned short* kb    = qb  + (size_t)NG*TT*DK;
    unsigned short* bvb   = kb  + (size_t)NG*TT*DK;             // NG*TT*DV
    unsigned short* Ab    = bvb + (size_t)NG*TT*DV;             // NG*TT*TT
    unsigned short* Utb   = Ab  + (size_t)NG*TT*TT;             // NG*TT*TT (transposed)
    unsigned short* Minvb = Utb + (size_t)NG*TT*TT;             // NG*8*64*64
    // phase 2 (output projection): ob aliases qb+kb; Wob aliases bvb;
    // bf16 partials P0..P3 alias Ab onward (dead after o_kern).
    unsigned short* ob  = bf;                                   // ROWS*VAL_DIM
    unsigned short* Wob = bvb;                                  // HID*VAL_DIM
    unsigned short* P0 = Ab;                                    // 4 x ROWS*HID bf16
    unsigned short* P1 = P0 + (size_t)ROWS * HID;
    unsigned short* P2 = P1 + (size_t)ROWS * HID;
    unsigned short* P3 = P2 + (size_t)ROWS * HID;

    dim3 blk(256);
    auto cblocks = [](size_t n) { size_t b = (n / 4 + 255) / 256; return (int)(b > 4096 ? 4096 : b); };

    // fused cast: x|Wq|Wk|Wv|Wg|Wa|Wb|pad -> contiguous bf16 block at xb
    Cast8 c8;
    c8.src[0] = x;  c8.src[1] = Wq; c8.src[2] = Wk; c8.src[3] = Wv;
    c8.src[4] = Wg; c8.src[5] = Wa; c8.src[6] = Wb; c8.src[7] = nullptr;
    c8.start4[0] = 0;
    c8.start4[1] = c8.start4[0] + ROWS*HID/4;
    c8.start4[2] = c8.start4[1] + KEY_DIM*HID/4;
    c8.start4[3] = c8.start4[2] + KEY_DIM*HID/4;
    c8.start4[4] = c8.start4[3] + VAL_DIM*HID/4;
    c8.start4[5] = c8.start4[4] + VAL_DIM*HID/4;
    c8.start4[6] = c8.start4[5] + NH*HID/4;
    c8.start4[7] = c8.start4[6] + NH*HID/4;
    c8.start4[8] = c8.start4[7] + (QW - OFF_A - 12)*HID/4;   // 116-row zero pad
    cast_multi<<<dim3(2048), blk, 0, stream>>>(c8, xb);

    // fused q|k|v|gate|a|b projection: 1168 blocks, bf16 C + fp32 a/b side
    gemm_qkvg<<<dim3((QW/128) * (ROWS/128)), blk, 0, stream>>>(
        xb, Wqb, qkvg, ab32, ROWS, QW, HID);

    cumsum_pack<<<dim3(NG), dim3(64), 0, stream>>>(ab32, A_log, dtb, cinc, cexc, barr);
    prep_norm<<<dim3(ROWS), dim3(384), 0, stream>>>(qkvg, decay, Dp, barr, qb, kb, bvb);
    a_mat<<<dim3(NG*36), blk, 0, stream>>>(kb, cinc, cexc, barr, Ab, Minvb);  // fused minv
    usolve<<<dim3(NG*16), blk, 0, stream>>>(Ab, Minvb, bvb, Utb);
    o_kern<<<dim3(NG*16), blk, 0, stream>>>(qb, kb, Utb, cinc, qkvg);
    epilogue<<<dim3(ROWS), dim3(384), 0, stream>>>(qkvg, onw, ob);

    // output projection: split-K=4, 1024 blocks, bf16 partials + fp32 reduce
    cast_f32_bf16<<<cblocks((size_t)HID*VAL_DIM), blk, 0, stream>>>(Wo, Wob, HID*VAL_DIM/4);
    gemm_nt_splitk4<<<dim3(4 * (HID/128) * (ROWS/128)), blk, 0, stream>>>(
        ob, Wob, P0, P1, P2, P3, ROWS, HID, VAL_DIM);
    add4_bf16<<<dim3(2048), blk, 0, stream>>>(out, P0, P1, P2, P3, ROWS*HID/4);
}

// Round 24
// 354.462 us; speedup vs baseline: 1.1916x; 1.0182x over previous
//
#include <hip/hip_runtime.h>
#include <hip/hip_bf16.h>
#include <math.h>

#define BB 4
#define TT 512
#define HID 2048
#define NH 6
#define DK 256
#define DV 512
#define ROWS (BB*TT)          /* 2048 */
#define KEY_DIM (NH*DK)       /* 1536 */
#define VAL_DIM (NH*DV)       /* 3072 */
#define NG (BB*NH)            /* 24 groups */
#define NC 8                  /* chunks */
#define CL 64                 /* chunk length */
#define QW 9344               /* fused row stride: q|k|v|gate|a|b|pad */
#define OFF_K 1536
#define OFF_V 3072
#define OFF_G 6144
#define OFF_A 9216

typedef __bf16 bf16x8 __attribute__((ext_vector_type(8)));
typedef float  f32x4  __attribute__((ext_vector_type(4)));

__device__ __forceinline__ unsigned short f2bf(float f) {
    unsigned int u = __float_as_uint(f);
    u = (u + 0x7FFFu + ((u >> 16) & 1u)) >> 16;
    return (unsigned short)u;
}
__device__ __forceinline__ float b2f(unsigned short u) {
    return __uint_as_float(((unsigned int)u) << 16);
}

// ---------------------------------------------------------------------------
// fp32 -> bf16 cast (RNE), vectorized. Single-source variant (Wo).
// ---------------------------------------------------------------------------
__global__ __launch_bounds__(256) void cast_f32_bf16(
    const float* __restrict__ src, unsigned short* __restrict__ dst, int n4)
{
    int stride = gridDim.x * 256;
    for (int i = blockIdx.x * 256 + threadIdx.x; i < n4; i += stride) {
        float4 v = ((const float4*)src)[i];
        ushort4 o;
        o.x = f2bf(v.x); o.y = f2bf(v.y); o.z = f2bf(v.z); o.w = f2bf(v.w);
        ((ushort4*)dst)[i] = o;
    }
}

// ---------------------------------------------------------------------------
// Multi-source fp32 -> bf16 cast: 8 sources (nullptr -> zero fill), one
// contiguous destination. Builds x | Wq | Wk | Wv | Wg | Wa | Wb | 0-pad.
// ---------------------------------------------------------------------------
struct Cast8 {
    const float* src[8];
    int start4[9];           // cumulative float4 offsets into dst
};
__global__ __launch_bounds__(256) void cast_multi(Cast8 c, unsigned short* __restrict__ dst)
{
    const int total = c.start4[8];
    int stride = gridDim.x * 256;
    for (int i = blockIdx.x * 256 + threadIdx.x; i < total; i += stride) {
        int s = 0;
        while (i >= c.start4[s + 1]) ++s;
        float4 v = make_float4(0.f, 0.f, 0.f, 0.f);
        if (c.src[s]) v = ((const float4*)c.src[s])[i - c.start4[s]];
        ushort4 o;
        o.x = f2bf(v.x); o.y = f2bf(v.y); o.z = f2bf(v.z); o.w = f2bf(v.w);
        ((ushort4*)dst)[i] = o;
    }
}

// ---------------------------------------------------------------------------
// out = p0+p1+p2+p3 (bf16 partials, fp32 sum/store; deterministic order).
// ---------------------------------------------------------------------------
__global__ __launch_bounds__(256) void add4_bf16(
    float* __restrict__ out, const unsigned short* __restrict__ p0,
    const unsigned short* __restrict__ p1, const unsigned short* __restrict__ p2,
    const unsigned short* __restrict__ p3, int n4)
{
    int stride = gridDim.x * 256;
    for (int i = blockIdx.x * 256 + threadIdx.x; i < n4; i += stride) {
        ushort4 a = ((const ushort4*)p0)[i];
        ushort4 b = ((const ushort4*)p1)[i];
        ushort4 c = ((const ushort4*)p2)[i];
        ushort4 d = ((const ushort4*)p3)[i];
        float4 o;
        o.x = ((b2f(a.x) + b2f(b.x)) + b2f(c.x)) + b2f(d.x);
        o.y = ((b2f(a.y) + b2f(b.y)) + b2f(c.y)) + b2f(d.y);
        o.z = ((b2f(a.z) + b2f(b.z)) + b2f(c.z)) + b2f(d.z);
        o.w = ((b2f(a.w) + b2f(b.w)) + b2f(c.w)) + b2f(d.w);
        ((float4*)out)[i] = o;
    }
}

// ---------------------------------------------------------------------------
// QKVG fused-projection GEMM v4: SAME 128x128/BK=32/2-phase template as the
// measured-best config, but 512 threads = 8 waves in 4x2 (wave tile 32x64,
// acc[2][4] = 32 regs/thread vs 64). Register footprint drop lifts the
// wave-residency cap: 4 blocks/CU (32 waves, full) vs ~2 before -> 2x
// cross-block overlap hiding the 2-phase barrier drain. Staging pattern,
// K-loop order, per-output MFMA chain identical -> bit-identical C.
// C bf16; a/b cols (OFF_A..+11) side-stored fp32.
// 1D grid + bijective XCD-chunked decode (grid %8 == 0 REQUIRED).
// ---------------------------------------------------------------------------
__global__ __launch_bounds__(512) void gemm_qkvg(
    const unsigned short* __restrict__ A, const unsigned short* __restrict__ B,
    unsigned short* __restrict__ C, float* __restrict__ ab32, int M, int N, int K)
{
    __shared__ __align__(16) unsigned short As[2][128 * 32];
    __shared__ __align__(16) unsigned short Bs[2][128 * 32];
    const int tid  = threadIdx.x;        // 0..511
    const int lane = tid & 63;
    const int wave = tid >> 6;           // 0..7
    const int per  = gridDim.x >> 3;
    const int lg   = (blockIdx.x & 7) * per + (blockIdx.x >> 3);
    const int bm = (lg & 15) * 128;      // by fast-varying (M = 2048)
    const int bn = (lg >> 4) * 128;      // B-tile, contiguous per XCD
    const int wr = (wave >> 1) * 32;     // 4 wave-rows of 32
    const int wc = (wave & 1) * 64;      // 2 wave-cols of 64
    const int fr = lane & 15;
    const int kg = lane >> 4;

    f32x4 acc[2][4] = {};

    // staging: 512 chunks per matrix, 1 chunk/thread each for A and B.
    // LDS chunk index == global chunk index e_ = tid (wave-uniform base +
    // lane*16B per global_load_lds semantics). Same layout as v3.
#define GSTAGE(buf, k0) do { \
    int e_  = tid; \
    int r_  = e_ >> 2; \
    int c8_ = (e_ & 3) * 8; \
    const unsigned short* ga_ = A + (size_t)(bm + r_) * K + (k0) + c8_; \
    const unsigned short* gb_ = B + (size_t)(bn + r_) * K + (k0) + c8_; \
    unsigned short* la_ = As[buf] + (size_t)(wave * 64) * 8; \
    unsigned short* lb_ = Bs[buf] + (size_t)(wave * 64) * 8; \
    __builtin_amdgcn_global_load_lds( \
        (const __attribute__((address_space(1))) void*)ga_, \
        (__attribute__((address_space(3))) void*)la_, 16, 0, 0); \
    __builtin_amdgcn_global_load_lds( \
        (const __attribute__((address_space(1))) void*)gb_, \
        (__attribute__((address_space(3))) void*)lb_, 16, 0, 0); \
} while (0)

    GSTAGE(0, 0);
    __syncthreads();

    int cur = 0;
    for (int k0 = 0; k0 < K; k0 += 32) {
        if (k0 + 32 < K) GSTAGE(cur ^ 1, k0 + 32);

        bf16x8 a[2], b[4];
        #pragma unroll
        for (int f = 0; f < 2; ++f)
            a[f] = *(const bf16x8*)&As[cur][(wr + f * 16 + fr) * 32 + kg * 8];
        #pragma unroll
        for (int f = 0; f < 4; ++f)
            b[f] = *(const bf16x8*)&Bs[cur][(wc + f * 16 + fr) * 32 + kg * 8];
        #pragma unroll
        for (int fm = 0; fm < 2; ++fm)
            #pragma unroll
            for (int fn = 0; fn < 4; ++fn)
                acc[fm][fn] = __builtin_amdgcn_mfma_f32_16x16x32_bf16(
                    a[fm], b[fn], acc[fm][fn], 0, 0, 0);

        __syncthreads();
        cur ^= 1;
    }
#undef GSTAGE

    #pragma unroll
    for (int fm = 0; fm < 2; ++fm)
        #pragma unroll
        for (int fn = 0; fn < 4; ++fn) {
            int col = bn + wc + fn * 16 + fr;
            bool isab = (col >= OFF_A) && (col < OFF_A + 12);
            #pragma unroll
            for (int i = 0; i < 4; ++i) {
                int row = bm + wr + fm * 16 + kg * 4 + i;
                float v = acc[fm][fn][i];
                C[(size_t)row * N + col] = f2bf(v);
                if (isab) ab32[(size_t)row * 12 + (col - OFF_A)] = v;
            }
        }
}

// ---------------------------------------------------------------------------
// Split-K=4 GEMM for the grid-starved Wo projection (M=2048,N=2048,K=3072):
// ONE dispatch, 1024 blocks. All four K-quarters store bf16 partials
// (P0..P3); add4_bf16 sums them in fp32 (deterministic).
// [Kept in the 4-wave 2-phase form as in-round control vs the 8-wave qkvg.]
// ---------------------------------------------------------------------------
__global__ __launch_bounds__(256) void gemm_nt_splitk4(
    const unsigned short* __restrict__ A, const unsigned short* __restrict__ B,
    unsigned short* __restrict__ C0, unsigned short* __restrict__ C1,
    unsigned short* __restrict__ C2, unsigned short* __restrict__ C3,
    int M, int N, int K)
{
    __shared__ __align__(16) unsigned short As[2][128 * 32];
    __shared__ __align__(16) unsigned short Bs[2][128 * 32];
    const int tid  = threadIdx.x;
    const int lane = tid & 63;
    const int wave = tid >> 6;
    const int per  = gridDim.x >> 3;
    const int lg   = (blockIdx.x & 7) * per + (blockIdx.x >> 3);
    const int kh   = lg & 3;
    const int bmn  = lg >> 2;
    const int bm = (bmn & 15) * 128;
    const int bn = (bmn >> 4) * 128;
    const int wr = (wave >> 1) * 64;
    const int wc = (wave & 1) * 64;
    const int fr = lane & 15;
    const int kg = lane >> 4;
    const int Kq = K >> 2;               // 768 -> 24 steps
    const int kbase = kh * Kq;

    f32x4 acc[4][4] = {};

#define GSTAGE(buf, k0) do { \
    _Pragma("unroll") \
    for (int s_ = 0; s_ < 2; ++s_) { \
        int e_  = s_ * 256 + tid; \
        int r_  = e_ >> 2; \
        int c8_ = (e_ & 3) * 8; \
        const unsigned short* ga_ = A + (size_t)(bm + r_) * K + (k0) + c8_; \
        const unsigned short* gb_ = B + (size_t)(bn + r_) * K + (k0) + c8_; \
        unsigned short* la_ = As[buf] + (size_t)(s_ * 256 + wave * 64) * 8; \
        unsigned short* lb_ = Bs[buf] + (size_t)(s_ * 256 + wave * 64) * 8; \
        __builtin_amdgcn_global_load_lds( \
            (const __attribute__((address_space(1))) void*)ga_, \
            (__attribute__((address_space(3))) void*)la_, 16, 0, 0); \
        __builtin_amdgcn_global_load_lds( \
            (const __attribute__((address_space(1))) void*)gb_, \
            (__attribute__((address_space(3))) void*)lb_, 16, 0, 0); \
    } \
} while (0)

    GSTAGE(0, kbase);
    __syncthreads();

    int cur = 0;
    for (int k0 = kbase; k0 < kbase + Kq; k0 += 32) {
        if (k0 + 32 < kbase + Kq) GSTAGE(cur ^ 1, k0 + 32);

        bf16x8 a[4], b[4];
        #pragma unroll
        for (int f = 0; f < 4; ++f) {
            a[f] = *(const bf16x8*)&As[cur][(wr + f * 16 + fr) * 32 + kg * 8];
            b[f] = *(const bf16x8*)&Bs[cur][(wc + f * 16 + fr) * 32 + kg * 8];
        }
        #pragma unroll
        for (int fm = 0; fm < 4; ++fm)
            #pragma unroll
            for (int fn = 0; fn < 4; ++fn)
                acc[fm][fn] = __builtin_amdgcn_mfma_f32_16x16x32_bf16(
                    a[fm], b[fn], acc[fm][fn], 0, 0, 0);

        __syncthreads();
        cur ^= 1;
    }
#undef GSTAGE

    unsigned short* C = (kh == 0) ? C0 : (kh == 1) ? C1 : (kh == 2) ? C2 : C3;
    #pragma unroll
    for (int fm = 0; fm < 4; ++fm)
        #pragma unroll
        for (int fn = 0; fn < 4; ++fn) {
            int col = bn + wc + fn * 16 + fr;
            #pragma unroll
            for (int i = 0; i < 4; ++i) {
                int row = bm + wr + fm * 16 + kg * 4 + i;
                C[(size_t)row * N + col] = f2bf(acc[fm][fn][i]);
            }
        }
}

// ---------------------------------------------------------------------------
// Per-group: a/b (fp32 side-store) -> g, beta; cumulative log-decay scan;
// writes cinc/cexc/barr. 24 blocks x 64 threads.
// ---------------------------------------------------------------------------
__global__ __launch_bounds__(64) void cumsum_pack(
    const float* __restrict__ ab32,
    const float* __restrict__ A_log, const float* __restrict__ dt_bias,
    float* __restrict__ cinc, float* __restrict__ cexc, float* __restrict__ barr)
{
    const int g = blockIdx.x;
    const int b = g / NH, h = g % NH;
    const int lane = threadIdx.x;
    const float nA = -expf(A_log[h]);
    const float db = dt_bias[h];
    float carry = 0.f;
    for (int c0 = 0; c0 < TT; c0 += 64) {
        int t = c0 + lane;
        size_t rbase = (size_t)(b*TT + t) * 12;
        float a  = ab32[rbase + h] + db;
        float sp = (a > 20.f) ? a : log1pf(expf(a));
        float gv = nA * sp;
        float bp = ab32[rbase + 6 + h];
        float x = gv;
        #pragma unroll
        for (int off = 1; off < 64; off <<= 1) {
            float n = __shfl_up(x, off);
            if (lane >= off) x += n;
        }
        float inc = carry + x;
        cinc[(size_t)g*TT + t] = inc;
        cexc[(size_t)g*TT + t] = inc - gv;
        barr[(size_t)g*TT + t] = 1.f / (1.f + expf(-bp));
        carry = __shfl(inc, 63);
    }
}

// ---------------------------------------------------------------------------
// Pointwise prep v2: barrier-free. 384 threads = 6 waves; wave h owns head h.
// ---------------------------------------------------------------------------
__global__ __launch_bounds__(384) void prep_norm(
    const unsigned short* __restrict__ qkvg,
    const float* __restrict__ decay, const float* __restrict__ D,
    const float* __restrict__ barr,
    unsigned short* __restrict__ qb, unsigned short* __restrict__ kb,
    unsigned short* __restrict__ bvb)
{
    const int row  = blockIdx.x;
    const int b    = row >> 9, t = row & 511;
    const int tid  = threadIdx.x;
    const int h    = tid >> 6;       // wave = head
    const int lane = tid & 63;

    size_t base = (size_t)row * QW + h * DK + lane * 4;
    ushort4 qu = *(const ushort4*)&qkvg[base];
    ushort4 ku = *(const ushort4*)&qkvg[base + OFF_K];
    float qv[4] = {b2f(qu.x), b2f(qu.y), b2f(qu.z), b2f(qu.w)};
    float kv[4] = {b2f(ku.x), b2f(ku.y), b2f(ku.z), b2f(ku.w)};
    const float coef = D[h] * (1.f / (1.f + expf(-decay[h])));
    float qc[4], kl[4];
    float sq = 0.f, sk = 0.f;
    #pragma unroll
    for (int i = 0; i < 4; ++i) {
        float ksil = kv[i] / (1.f + expf(-kv[i]));
        float qsil = qv[i] / (1.f + expf(-qv[i]));
        qc[i] = qsil - coef * ksil;
        kl[i] = ksil;
        sq += qc[i] * qc[i];
        sk += ksil * ksil;
    }
    #pragma unroll
    for (int off = 32; off >= 1; off >>= 1) {
        sq += __shfl_xor(sq, off);
        sk += __shfl_xor(sk, off);
    }
    float qinv = 0.0625f / fmaxf(sqrtf(sq), 1e-12f);
    float kinv = 1.f     / fmaxf(sqrtf(sk), 1e-12f);
    size_t gidx = (((size_t)(b*NH + h)) * TT + t) * DK + lane * 4;
    ushort4 qo, ko;
    qo.x = f2bf(qc[0]*qinv); qo.y = f2bf(qc[1]*qinv);
    qo.z = f2bf(qc[2]*qinv); qo.w = f2bf(qc[3]*qinv);
    ko.x = f2bf(kl[0]*kinv); ko.y = f2bf(kl[1]*kinv);
    ko.z = f2bf(kl[2]*kinv); ko.w = f2bf(kl[3]*kinv);
    *(ushort4*)&qb[gidx] = qo;
    *(ushort4*)&kb[gidx] = ko;

    const int jj0 = tid * 8;
    const int h2  = jj0 >> 9;
    const int dv  = jj0 & 511;
    float bt = barr[((size_t)(b*NH + h2)) * TT + t];
    const unsigned short* vp = &qkvg[(size_t)row * QW + OFF_V + jj0];
    unsigned short* bp = &bvb[(((size_t)(b*NH + h2)) * TT + t) * DV + dv];
    ushort4 v0 = *(const ushort4*)vp;
    ushort4 v1 = *(const ushort4*)(vp + 4);
    unsigned short vi[8] = {v0.x, v0.y, v0.z, v0.w, v1.x, v1.y, v1.z, v1.w};
    ushort4 o0, o1;
    unsigned short vo[8];
    #pragma unroll
    for (int i = 0; i < 8; ++i) {
        float xv = b2f(vi[i]);
        float sv = xv / (1.f + expf(-xv));
        vo[i] = f2bf(bt * sv);
    }
    o0.x = vo[0]; o0.y = vo[1]; o0.z = vo[2]; o0.w = vo[3];
    o1.x = vo[4]; o1.y = vo[5]; o1.z = vo[6]; o1.w = vo[7];
    *(ushort4*)bp       = o0;
    *(ushort4*)(bp + 4) = o1;
}

// ---------------------------------------------------------------------------
// A-matrix tiles: A[i,j] = beta_i * exp(cexc_i - cinc_j) * (k_i . k_j), j<i.
// Diagonal blocks (l==m) ALSO compute the unit-lower-triangular inverse of
// (I + A_mm) in-kernel (fused minv).
// ---------------------------------------------------------------------------
__global__ __launch_bounds__(256) void a_mat(
    const unsigned short* __restrict__ kb, const float* __restrict__ cinc,
    const float* __restrict__ cexc, const float* __restrict__ barr,
    unsigned short* __restrict__ Ab, unsigned short* __restrict__ Minvb)
{
    __shared__ __align__(16) unsigned short Asub[64][72];
    __shared__ __align__(16) float Xt[64][68];

    const int blk = blockIdx.x;
    const int g = blk / 36;
    int p = blk % 36, m = 0, acc0 = 0;
    while (p >= acc0 + m + 1) { acc0 += m + 1; ++m; }
    const int l = p - acc0;
    const int tid = threadIdx.x, lane = tid & 63, w = tid >> 6;
    const int fr = lane & 15, kg = lane >> 4;
    const unsigned short* Km = kb + (((size_t)g*TT) + m*CL) * DK;
    const unsigned short* Kl = kb + (((size_t)g*TT) + l*CL) * DK;
    f32x4 acc[4] = {};
    #pragma unroll
    for (int ks = 0; ks < 8; ++ks) {
        bf16x8 a = *(const bf16x8*)(Km + (size_t)(w*16 + fr)*DK + ks*32 + kg*8);
        bf16x8 bb[4];
        #pragma unroll
        for (int fn = 0; fn < 4; ++fn)
            bb[fn] = *(const bf16x8*)(Kl + (size_t)(fn*16 + fr)*DK + ks*32 + kg*8);
        #pragma unroll
        for (int fn = 0; fn < 4; ++fn)
            acc[fn] = __builtin_amdgcn_mfma_f32_16x16x32_bf16(a, bb[fn], acc[fn], 0, 0, 0);
    }
    const float* ci = cinc + (size_t)g*TT;
    const float* ce = cexc + (size_t)g*TT;
    const float* bb2 = barr + (size_t)g*TT;
    const bool diag = (l == m);
    #pragma unroll
    for (int fn = 0; fn < 4; ++fn) {
        int jl = fn*16 + fr;
        int tj = l*CL + jl;
        float cj = ci[tj];
        #pragma unroll
        for (int r = 0; r < 4; ++r) {
            int il = w*16 + kg*4 + r;
            int ti = m*CL + il;
            float val = 0.f;
            if (tj < ti) val = bb2[ti] * __expf(ce[ti] - cj) * acc[fn][r];
            unsigned short vb = f2bf(val);
            Ab[((size_t)g*TT + ti)*TT + tj] = vb;
            if (diag) Asub[il][jl] = vb;
        }
    }

    if (diag) {
        __syncthreads();                 // Asub staged by all 4 waves
        if (tid < 64) {                  // wave 0: wave-synchronous inverse
            const int col = tid;
            #pragma unroll
            for (int t4 = 0; t4 < 17; ++t4)
                *(float4*)&Xt[col][t4*4] = make_float4(0.f, 0.f, 0.f, 0.f);
            Xt[col][col] = 1.f;
            #pragma unroll 1
            for (int i = 1; i < 64; ++i) {
                const int nch = (i + 7) >> 3;
                float s = 0.f;
                #pragma unroll 1
                for (int c8 = 0; c8 < nch; ++c8) {
                    ushort4 a0 = *(const ushort4*)&Asub[i][c8*8];
                    ushort4 a1 = *(const ushort4*)&Asub[i][c8*8 + 4];
                    float4  x0 = *(const float4*)&Xt[col][c8*8];
                    float4  x1 = *(const float4*)&Xt[col][c8*8 + 4];
                    s += b2f(a0.x)*x0.x; s += b2f(a0.y)*x0.y;
                    s += b2f(a0.z)*x0.z; s += b2f(a0.w)*x0.w;
                    s += b2f(a1.x)*x1.x; s += b2f(a1.y)*x1.y;
                    s += b2f(a1.z)*x1.z; s += b2f(a1.w)*x1.w;
                }
                if (col < i) Xt[col][i] = -s;
            }
            unsigned short* outp = Minvb + (size_t)(g*8 + m) * 4096;
            #pragma unroll 4
            for (int r = 0; r < 64; ++r)
                outp[(size_t)r*64 + col] = f2bf(Xt[col][r]);
        }
    }
}

// ---------------------------------------------------------------------------
// U-solve v3: (I+A) U = beta*V, block forward substitution over 8 chunks.
// grid = 24 groups x 16 v-slices(32) = 384 blocks. Utb[g][v][t] bf16.
// Block's whole U slice mirrored in LDS (Uls[32][520]); all chunk-to-chunk
// U reads come from LDS (no global RAW round-trips). Bit-identical.
// ---------------------------------------------------------------------------
__global__ __launch_bounds__(256) void usolve(
    const unsigned short* __restrict__ Ab, const unsigned short* __restrict__ Minvb,
    const unsigned short* __restrict__ bvb, unsigned short* __restrict__ Utb)
{
    const int blk = blockIdx.x;
    const int g = blk >> 4, vs = blk & 15;
    const int tid = threadIdx.x, lane = tid & 63, w = tid >> 6;
    const int fr = lane & 15, kg = lane >> 4;
    __shared__ __align__(16) unsigned short TACC[2][32][40];
    __shared__ __align__(16) unsigned short Uls[32][520];   // [v][t], pad->2-way

    for (int m = 0; m < NC; ++m) {
        f32x4 acc[2] = {};
        for (int l = 0; l < m; ++l) {
            const unsigned short* Aml = Ab + (((size_t)g*TT) + m*CL)*TT + l*CL;
            #pragma unroll
            for (int ks = 0; ks < 2; ++ks) {
                bf16x8 a = *(const bf16x8*)(Aml + (size_t)(w*16 + fr)*TT + ks*32 + kg*8);
                bf16x8 bb[2];
                #pragma unroll
                for (int fn = 0; fn < 2; ++fn)
                    bb[fn] = *(const bf16x8*)&Uls[fn*16 + fr][l*CL + ks*32 + kg*8];
                #pragma unroll
                for (int fn = 0; fn < 2; ++fn)
                    acc[fn] = __builtin_amdgcn_mfma_f32_16x16x32_bf16(a, bb[fn], acc[fn], 0, 0, 0);
            }
        }
        __syncthreads();
        const unsigned short* bvg = bvb + (((size_t)g*TT) + m*CL)*DV + vs*32;
        #pragma unroll
        for (int fn = 0; fn < 2; ++fn) {
            int v = fn*16 + fr;
            #pragma unroll
            for (int r = 0; r < 4; ++r) {
                int i = w*16 + kg*4 + r;
                float rhs = b2f(bvg[(size_t)i*DV + v]) - acc[fn][r];
                TACC[i >> 5][v][i & 31] = f2bf(rhs);
            }
        }
        __syncthreads();
        const unsigned short* Mi = Minvb + (size_t)(g*8 + m) * 4096;
        f32x4 acc2[2] = {};
        #pragma unroll
        for (int ks = 0; ks < 2; ++ks) {
            bf16x8 a = *(const bf16x8*)(Mi + (size_t)(w*16 + fr)*64 + ks*32 + kg*8);
            bf16x8 bb[2];
            #pragma unroll
            for (int fn = 0; fn < 2; ++fn)
                bb[fn] = *(const bf16x8*)&TACC[ks][fn*16 + fr][kg*8];
            #pragma unroll
            for (int fn = 0; fn < 2; ++fn)
                acc2[fn] = __builtin_amdgcn_mfma_f32_16x16x32_bf16(a, bb[fn], acc2[fn], 0, 0, 0);
        }
        unsigned short* Um = Utb + (((size_t)g*TT) + vs*32)*TT + m*CL;
        #pragma unroll
        for (int fn = 0; fn < 2; ++fn) {
            int v = fn*16 + fr;
            #pragma unroll
            for (int r = 0; r < 4; ++r) {
                int i = w*16 + kg*4 + r;
                unsigned short uv = f2bf(acc2[fn][r]);
                Um[(size_t)v*TT + i] = uv;          // for o_kern
                Uls[v][m*CL + i]    = uv;           // for later chunks (LDS)
            }
        }
        __syncthreads();   // LDS U-chunk visible before next chunk reads it
    }
}

// ---------------------------------------------------------------------------
// Output: o_i = sum_{j<=i} exp(c_i - c_j)*(q_i . k_j) * u_j.
// Block = (g, m-pair {p, 7-p}, v-quarter 128). 9 balanced l-iters per block.
// K/U tiles async-staged into double-buffered swizzled LDS; Q in registers.
// Writes o bf16 into the fused qkvg buffer's (dead) v columns @3072.
// ---------------------------------------------------------------------------
__global__ __launch_bounds__(256) void o_kern(
    const unsigned short* __restrict__ qb, const unsigned short* __restrict__ kb,
    const unsigned short* __restrict__ Utb, const float* __restrict__ cinc,
    unsigned short* __restrict__ qkvg)
{
    __shared__ __align__(16) unsigned short Kls[2][64*256];   // 64 KB
    __shared__ __align__(16) unsigned short Uls[2][128*64];   // 32 KB
    __shared__ __align__(16) unsigned short Ps[2][64][40];    // 10 KB
    __shared__ float cgl[TT];                                 // 2 KB

    const int blk = blockIdx.x;
    const int g  = blk >> 4;
    const int rm = blk & 15;
    const int pr = rm >> 2;
    const int vq = rm & 3;
    const int b = g / NH, h = g % NH;
    const int tid = threadIdx.x, lane = tid & 63, w = tid >> 6;
    const int fr = lane & 15, kg = lane >> 4;

    const unsigned short* kgrp = kb  + (size_t)g*TT*DK;
    const unsigned short* ugrp = Utb + ((size_t)g*TT + vq*128)*TT;

#define STAGE_K(buf, l) do { \
    _Pragma("unroll") \
    for (int s_ = 0; s_ < 8; ++s_) { \
        int slot_ = s_*256 + tid; \
        int gc_ = slot_ ^ ((slot_ >> 5) & 7); \
        const unsigned short* ga_ = kgrp + (size_t)(l)*CL*DK + gc_*8; \
        __builtin_amdgcn_global_load_lds( \
            (const __attribute__((address_space(1))) void*)ga_, \
            (__attribute__((address_space(3))) void*)&Kls[buf][slot_*8], 16, 0, 0); \
    } \
} while (0)

#define STAGE_U(buf, l) do { \
    _Pragma("unroll") \
    for (int s_ = 0; s_ < 4; ++s_) { \
        int slot_ = s_*256 + tid; \
        int gc_ = slot_ ^ ((slot_ >> 3) & 7); \
        const unsigned short* ga_ = ugrp + (size_t)(gc_ >> 3)*TT + (l)*CL + (gc_ & 7)*8; \
        __builtin_amdgcn_global_load_lds( \
            (const __attribute__((address_space(1))) void*)ga_, \
            (__attribute__((address_space(3))) void*)&Uls[buf][slot_*8], 16, 0, 0); \
    } \
} while (0)

    cgl[tid]       = cinc[(size_t)g*TT + tid];
    cgl[tid + 256] = cinc[(size_t)g*TT + tid + 256];
    STAGE_K(0, 0);
    STAGE_U(0, 0);
    __syncthreads();

    int cur = 0;
    #pragma unroll 1
    for (int mi_idx = 0; mi_idx < 2; ++mi_idx) {
        const int mi = mi_idx ? (7 - pr) : pr;
        const unsigned short* Qm = qb + (((size_t)g*TT) + mi*CL) * DK + (size_t)(w*16 + fr)*DK;
        bf16x8 qf[8];
        #pragma unroll
        for (int ks = 0; ks < 8; ++ks) qf[ks] = *(const bf16x8*)(Qm + ks*32 + kg*8);

        f32x4 acc[8] = {};
        #pragma unroll 1
        for (int l = 0; l <= mi; ++l) {
            if (l < mi)            { STAGE_K(cur^1, l+1); STAGE_U(cur^1, l+1); }
            else if (mi_idx == 0)  { STAGE_K(cur^1, 0);   STAGE_U(cur^1, 0);   }

            f32x4 sacc[4] = {};
            #pragma unroll
            for (int ks = 0; ks < 8; ++ks) {
                bf16x8 bbf[4];
                #pragma unroll
                for (int fn = 0; fn < 4; ++fn) {
                    int row = fn*16 + fr;
                    int slot = (row*32 + ks*4 + kg) ^ (row & 7);
                    bbf[fn] = *(const bf16x8*)&Kls[cur][slot*8];
                }
                #pragma unroll
                for (int fn = 0; fn < 4; ++fn)
                    sacc[fn] = __builtin_amdgcn_mfma_f32_16x16x32_bf16(qf[ks], bbf[fn], sacc[fn], 0, 0, 0);
            }
            __syncthreads();

            #pragma unroll
            for (int fn = 0; fn < 4; ++fn) {
                int jl = fn*16 + fr;
                float cjv = cgl[l*CL + jl];
                #pragma unroll
                for (int r = 0; r < 4; ++r) {
                    int il = w*16 + kg*4 + r;
                    float val = ((l*CL + jl) <= (mi*CL + il))
                              ? sacc[fn][r] * __expf(cgl[mi*CL + il] - cjv) : 0.f;
                    Ps[jl >> 5][il][jl & 31] = f2bf(val);
                }
            }
            __syncthreads();

            #pragma unroll
            for (int ks = 0; ks < 2; ++ks) {
                bf16x8 a = *(const bf16x8*)&Ps[ks][w*16 + fr][kg*8];
                bf16x8 bbf[8];
                #pragma unroll
                for (int fn = 0; fn < 8; ++fn) {
                    int vrow = fn*16 + fr;
                    int slot = (vrow*8 + ks*4 + kg) ^ (vrow & 7);
                    bbf[fn] = *(const bf16x8*)&Uls[cur][slot*8];
                }
                #pragma unroll
                for (int fn = 0; fn < 8; ++fn)
                    acc[fn] = __builtin_amdgcn_mfma_f32_16x16x32_bf16(a, bbf[fn], acc[fn], 0, 0, 0);
            }
            __syncthreads();
            cur ^= 1;
        }

        // store o (bf16) into fused buffer (dead v columns): [row][QW]@3072
        unsigned short* ob = qkvg + ((size_t)(b*TT + mi*CL)) * QW + OFF_V + h*DV + vq*128;
        #pragma unroll
        for (int fn = 0; fn < 8; ++fn) {
            int v = fn*16 + fr;
            #pragma unroll
            for (int r = 0; r < 4; ++r) {
                int il = w*16 + kg*4 + r;
                ob[(size_t)il*QW + v] = f2bf(acc[fn][r]);
            }
        }
    }
#undef STAGE_K
#undef STAGE_U
}

// ---------------------------------------------------------------------------
// Gated RMSNorm epilogue v2: barrier-free. 384 threads = 6 waves; wave h owns
// head h: 8 elems/lane, wave-local shfl reduction, 16B loads/stores.
// ---------------------------------------------------------------------------
__global__ __launch_bounds__(384) void epilogue(
    const unsigned short* __restrict__ qkvg, const float* __restrict__ wnorm,
    unsigned short* __restrict__ ob)
{
    const int row  = blockIdx.x;
    const int tid  = threadIdx.x;
    const int h    = tid >> 6;
    const int lane = tid & 63;

    size_t base = (size_t)row * QW + OFF_V + h * DV + lane * 8;
    ushort4 a0 = *(const ushort4*)&qkvg[base];
    ushort4 a1 = *(const ushort4*)&qkvg[base + 4];
    unsigned short oi[8] = {a0.x, a0.y, a0.z, a0.w, a1.x, a1.y, a1.z, a1.w};
    float ov[8];
    float ss = 0.f;
    #pragma unroll
    for (int i = 0; i < 8; ++i) { ov[i] = b2f(oi[i]); ss += ov[i]*ov[i]; }
    #pragma unroll
    for (int off = 32; off >= 1; off >>= 1) ss += __shfl_xor(ss, off);
    float irms = rsqrtf(ss * (1.f / DV) + 1e-6f);

    size_t gbase = (size_t)row * QW + OFF_G + h * DV + lane * 8;
    ushort4 g0 = *(const ushort4*)&qkvg[gbase];
    ushort4 g1 = *(const ushort4*)&qkvg[gbase + 4];
    unsigned short gi[8] = {g0.x, g0.y, g0.z, g0.w, g1.x, g1.y, g1.z, g1.w};

    unsigned short vo[8];
    #pragma unroll
    for (int i = 0; i < 8; ++i) {
        float gv = b2f(gi[i]);
        float wv = wnorm[lane*8 + i];
        vo[i] = f2bf(ov[i] * irms * wv * (1.f / (1.f + expf(-gv))));
    }
    size_t obase = (size_t)row * VAL_DIM + h * DV + lane * 8;
    ushort4 w0, w1;
    w0.x = vo[0]; w0.y = vo[1]; w0.z = vo[2]; w0.w = vo[3];
    w1.x = vo[4]; w1.y = vo[5]; w1.z = vo[6]; w1.w = vo[7];
    *(ushort4*)&ob[obase]     = w0;
    *(ushort4*)&ob[obase + 4] = w1;
}

// ---------------------------------------------------------------------------
extern "C" void kernel_launch(void* const* d_in, const int* in_sizes, int n_in,
                              void* d_out, int out_size, void* d_ws, size_t ws_size,
                              hipStream_t stream)
{
    const float* x     = (const float*)d_in[0];
    const float* Wq    = (const float*)d_in[1];
    const float* Wk    = (const float*)d_in[2];
    const float* Wv    = (const float*)d_in[3];
    const float* Wa    = (const float*)d_in[4];
    const float* Wb    = (const float*)d_in[5];
    const float* decay = (const float*)d_in[6];
    const float* Dp    = (const float*)d_in[7];
    const float* A_log = (const float*)d_in[8];
    const float* dtb   = (const float*)d_in[9];
    const float* Wg    = (const float*)d_in[10];
    const float* Wo    = (const float*)d_in[11];
    const float* onw   = (const float*)d_in[12];
    float* out = (float*)d_out;

    unsigned short* qkvg = (unsigned short*)d_ws;            // ROWS*QW bf16 (38.3 MB)
    float* ab32 = (float*)(qkvg + (size_t)ROWS * QW);        // ROWS*12 fp32 (a|b cols)
    float* cinc = ab32 + (size_t)ROWS * 12;                  // NG*TT
    float* cexc = cinc + (size_t)NG * TT;
    float* barr = cexc + (size_t)NG * TT;
    unsigned short* bf = (unsigned short*)(barr + (size_t)NG * TT);

    // phase 1 (projections): weight block is one contiguous [9344][2048]
    // bf16 matrix (order q,k,v,g,a,b,zero-pad).
    unsigned short* xb  = bf;                                   // ROWS*HID
    unsigned short* Wqb = xb  + (size_t)ROWS * HID;
    // phase R (chunked recurrence) — aliases phase 1 (dead by then)
    unsigned short* qb    = bf;                                 // NG*TT*DK
    unsigned short* kb    = qb  + (size_t)NG*TT*DK;
    unsigned short* bvb   = kb  + (size_t)NG*TT*DK;             // NG*TT*DV
    unsigned short* Ab    = bvb + (size_t)NG*TT*DV;             // NG*TT*TT
    unsigned short* Utb   = Ab  + (size_t)NG*TT*TT;             // NG*TT*TT (transposed)
    unsigned short* Minvb = Utb + (size_t)NG*TT*TT;             // NG*8*64*64
    // phase 2 (output projection): ob aliases qb+kb; Wob aliases bvb;
    // bf16 partials P0..P3 alias Ab onward (dead after o_kern).
    unsigned short* ob  = bf;                                   // ROWS*VAL_DIM
    unsigned short* Wob = bvb;                                  // HID*VAL_DIM
    unsigned short* P0 = Ab;                                    // 4 x ROWS*HID bf16
    unsigned short* P1 = P0 + (size_t)ROWS * HID;
    unsigned short* P2 = P1 + (size_t)ROWS * HID;
    unsigned short* P3 = P2 + (size_t)ROWS * HID;

    dim3 blk(256);
    auto cblocks = [](size_t n) { size_t b = (n / 4 + 255) / 256; return (int)(b > 4096 ? 4096 : b); };

    // fused cast: x|Wq|Wk|Wv|Wg|Wa|Wb|pad -> contiguous bf16 block at xb
    Cast8 c8;
    c8.src[0] = x;  c8.src[1] = Wq; c8.src[2] = Wk; c8.src[3] = Wv;
    c8.src[4] = Wg; c8.src[5] = Wa; c8.src[6] = Wb; c8.src[7] = nullptr;
    c8.start4[0] = 0;
    c8.start4[1] = c8.start4[0] + ROWS*HID/4;
    c8.start4[2] = c8.start4[1] + KEY_DIM*HID/4;
    c8.start4[3] = c8.start4[2] + KEY_DIM*HID/4;
    c8.start4[4] = c8.start4[3] + VAL_DIM*HID/4;
    c8.start4[5] = c8.start4[4] + VAL_DIM*HID/4;
    c8.start4[6] = c8.start4[5] + NH*HID/4;
    c8.start4[7] = c8.start4[6] + NH*HID/4;
    c8.start4[8] = c8.start4[7] + (QW - OFF_A - 12)*HID/4;   // 116-row zero pad
    cast_multi<<<dim3(2048), blk, 0, stream>>>(c8, xb);

    // fused q|k|v|gate|a|b projection: 1168 blocks, 8-wave 2-phase template
    gemm_qkvg<<<dim3((QW/128) * (ROWS/128)), dim3(512), 0, stream>>>(
        xb, Wqb, qkvg, ab32, ROWS, QW, HID);

    cumsum_pack<<<dim3(NG), dim3(64), 0, stream>>>(ab32, A_log, dtb, cinc, cexc, barr);
    prep_norm<<<dim3(ROWS), dim3(384), 0, stream>>>(qkvg, decay, Dp, barr, qb, kb, bvb);
    a_mat<<<dim3(NG*36), blk, 0, stream>>>(kb, cinc, cexc, barr, Ab, Minvb);  // fused minv
    usolve<<<dim3(NG*16), blk, 0, stream>>>(Ab, Minvb, bvb, Utb);
    o_kern<<<dim3(NG*16), blk, 0, stream>>>(qb, kb, Utb, cinc, qkvg);
    epilogue<<<dim3(ROWS), dim3(384), 0, stream>>>(qkvg, onw, ob);

    // output projection: split-K=4, 1024 blocks, bf16 partials + fp32 reduce
    cast_f32_bf16<<<cblocks((size_t)HID*VAL_DIM), blk, 0, stream>>>(Wo, Wob, HID*VAL_DIM/4);
    gemm_nt_splitk4<<<dim3(4 * (HID/128) * (ROWS/128)), blk, 0, stream>>>(
        ob, Wob, P0, P1, P2, P3, ROWS, HID, VAL_DIM);
    add4_bf16<<<dim3(2048), blk, 0, stream>>>(out, P0, P1, P2, P3, ROWS*HID/4);
}

// Round 25
// 352.530 us; speedup vs baseline: 1.1981x; 1.0055x over previous
//
#include <hip/hip_runtime.h>
#include <hip/hip_bf16.h>
#include <math.h>

#define BB 4
#define TT 512
#define HID 2048
#define NH 6
#define DK 256
#define DV 512
#define ROWS (BB*TT)          /* 2048 */
#define KEY_DIM (NH*DK)       /* 1536 */
#define VAL_DIM (NH*DV)       /* 3072 */
#define NG (BB*NH)            /* 24 groups */
#define NC 8                  /* chunks */
#define CL 64                 /* chunk length */
#define QW 9344               /* fused row stride: q|k|v|gate|a|b|pad */
#define OFF_K 1536
#define OFF_V 3072
#define OFF_G 6144
#define OFF_A 9216

typedef __bf16 bf16x8 __attribute__((ext_vector_type(8)));
typedef float  f32x4  __attribute__((ext_vector_type(4)));

__device__ __forceinline__ unsigned short f2bf(float f) {
    unsigned int u = __float_as_uint(f);
    u = (u + 0x7FFFu + ((u >> 16) & 1u)) >> 16;
    return (unsigned short)u;
}
__device__ __forceinline__ float b2f(unsigned short u) {
    return __uint_as_float(((unsigned int)u) << 16);
}

// ---------------------------------------------------------------------------
// fp32 -> bf16 cast (RNE), vectorized. Single-source variant (Wo).
// ---------------------------------------------------------------------------
__global__ __launch_bounds__(256) void cast_f32_bf16(
    const float* __restrict__ src, unsigned short* __restrict__ dst, int n4)
{
    int stride = gridDim.x * 256;
    for (int i = blockIdx.x * 256 + threadIdx.x; i < n4; i += stride) {
        float4 v = ((const float4*)src)[i];
        ushort4 o;
        o.x = f2bf(v.x); o.y = f2bf(v.y); o.z = f2bf(v.z); o.w = f2bf(v.w);
        ((ushort4*)dst)[i] = o;
    }
}

// ---------------------------------------------------------------------------
// Multi-source fp32 -> bf16 cast: 8 sources (nullptr -> zero fill), one
// contiguous destination. Builds x | Wq | Wk | Wv | Wg | Wa | Wb | 0-pad.
// ---------------------------------------------------------------------------
struct Cast8 {
    const float* src[8];
    int start4[9];           // cumulative float4 offsets into dst
};
__global__ __launch_bounds__(256) void cast_multi(Cast8 c, unsigned short* __restrict__ dst)
{
    const int total = c.start4[8];
    int stride = gridDim.x * 256;
    for (int i = blockIdx.x * 256 + threadIdx.x; i < total; i += stride) {
        int s = 0;
        while (i >= c.start4[s + 1]) ++s;
        float4 v = make_float4(0.f, 0.f, 0.f, 0.f);
        if (c.src[s]) v = ((const float4*)c.src[s])[i - c.start4[s]];
        ushort4 o;
        o.x = f2bf(v.x); o.y = f2bf(v.y); o.z = f2bf(v.z); o.w = f2bf(v.w);
        ((ushort4*)dst)[i] = o;
    }
}

// ---------------------------------------------------------------------------
// out = p0+p1+p2+p3 (bf16 partials, fp32 sum/store; deterministic order).
// ---------------------------------------------------------------------------
__global__ __launch_bounds__(256) void add4_bf16(
    float* __restrict__ out, const unsigned short* __restrict__ p0,
    const unsigned short* __restrict__ p1, const unsigned short* __restrict__ p2,
    const unsigned short* __restrict__ p3, int n4)
{
    int stride = gridDim.x * 256;
    for (int i = blockIdx.x * 256 + threadIdx.x; i < n4; i += stride) {
        ushort4 a = ((const ushort4*)p0)[i];
        ushort4 b = ((const ushort4*)p1)[i];
        ushort4 c = ((const ushort4*)p2)[i];
        ushort4 d = ((const ushort4*)p3)[i];
        float4 o;
        o.x = ((b2f(a.x) + b2f(b.x)) + b2f(c.x)) + b2f(d.x);
        o.y = ((b2f(a.y) + b2f(b.y)) + b2f(c.y)) + b2f(d.y);
        o.z = ((b2f(a.z) + b2f(b.z)) + b2f(c.z)) + b2f(d.z);
        o.w = ((b2f(a.w) + b2f(b.w)) + b2f(c.w)) + b2f(d.w);
        ((float4*)out)[i] = o;
    }
}

// ---------------------------------------------------------------------------
// QKVG fused-projection GEMM v4 (R24 measured-best): 128x128/BK=32/2-phase,
// 512 threads = 8 waves in 4x2 (wave tile 32x64, acc[2][4] = 32 regs).
// VGPR 36 -> 4 blocks/CU (49% occupancy measured), MfmaUtil 31.6%.
// C bf16; a/b cols (OFF_A..+11) side-stored fp32.
// 1D grid + bijective XCD-chunked decode (grid %8 == 0 REQUIRED).
// ---------------------------------------------------------------------------
__global__ __launch_bounds__(512) void gemm_qkvg(
    const unsigned short* __restrict__ A, const unsigned short* __restrict__ B,
    unsigned short* __restrict__ C, float* __restrict__ ab32, int M, int N, int K)
{
    __shared__ __align__(16) unsigned short As[2][128 * 32];
    __shared__ __align__(16) unsigned short Bs[2][128 * 32];
    const int tid  = threadIdx.x;        // 0..511
    const int lane = tid & 63;
    const int wave = tid >> 6;           // 0..7
    const int per  = gridDim.x >> 3;
    const int lg   = (blockIdx.x & 7) * per + (blockIdx.x >> 3);
    const int bm = (lg & 15) * 128;      // by fast-varying (M = 2048)
    const int bn = (lg >> 4) * 128;      // B-tile, contiguous per XCD
    const int wr = (wave >> 1) * 32;     // 4 wave-rows of 32
    const int wc = (wave & 1) * 64;      // 2 wave-cols of 64
    const int fr = lane & 15;
    const int kg = lane >> 4;

    f32x4 acc[2][4] = {};

#define GSTAGE(buf, k0) do { \
    int e_  = tid; \
    int r_  = e_ >> 2; \
    int c8_ = (e_ & 3) * 8; \
    const unsigned short* ga_ = A + (size_t)(bm + r_) * K + (k0) + c8_; \
    const unsigned short* gb_ = B + (size_t)(bn + r_) * K + (k0) + c8_; \
    unsigned short* la_ = As[buf] + (size_t)(wave * 64) * 8; \
    unsigned short* lb_ = Bs[buf] + (size_t)(wave * 64) * 8; \
    __builtin_amdgcn_global_load_lds( \
        (const __attribute__((address_space(1))) void*)ga_, \
        (__attribute__((address_space(3))) void*)la_, 16, 0, 0); \
    __builtin_amdgcn_global_load_lds( \
        (const __attribute__((address_space(1))) void*)gb_, \
        (__attribute__((address_space(3))) void*)lb_, 16, 0, 0); \
} while (0)

    GSTAGE(0, 0);
    __syncthreads();

    int cur = 0;
    for (int k0 = 0; k0 < K; k0 += 32) {
        if (k0 + 32 < K) GSTAGE(cur ^ 1, k0 + 32);

        bf16x8 a[2], b[4];
        #pragma unroll
        for (int f = 0; f < 2; ++f)
            a[f] = *(const bf16x8*)&As[cur][(wr + f * 16 + fr) * 32 + kg * 8];
        #pragma unroll
        for (int f = 0; f < 4; ++f)
            b[f] = *(const bf16x8*)&Bs[cur][(wc + f * 16 + fr) * 32 + kg * 8];
        #pragma unroll
        for (int fm = 0; fm < 2; ++fm)
            #pragma unroll
            for (int fn = 0; fn < 4; ++fn)
                acc[fm][fn] = __builtin_amdgcn_mfma_f32_16x16x32_bf16(
                    a[fm], b[fn], acc[fm][fn], 0, 0, 0);

        __syncthreads();
        cur ^= 1;
    }
#undef GSTAGE

    #pragma unroll
    for (int fm = 0; fm < 2; ++fm)
        #pragma unroll
        for (int fn = 0; fn < 4; ++fn) {
            int col = bn + wc + fn * 16 + fr;
            bool isab = (col >= OFF_A) && (col < OFF_A + 12);
            #pragma unroll
            for (int i = 0; i < 4; ++i) {
                int row = bm + wr + fm * 16 + kg * 4 + i;
                float v = acc[fm][fn][i];
                C[(size_t)row * N + col] = f2bf(v);
                if (isab) ab32[(size_t)row * 12 + (col - OFF_A)] = v;
            }
        }
}

// ---------------------------------------------------------------------------
// Split-K=4 GEMM v2 for the Wo projection (M=2048,N=2048,K=3072):
// SAME 8-wave repartition as gemm_qkvg v4 (wave tile 32x64, acc[2][4] =
// 32 regs -> doubled wave residency). Staging/K-loop/per-output chain
// identical to v1 -> bit-identical partials. ONE dispatch, 1024 blocks;
// kh quarters store bf16 partials P0..P3, summed fp32 by add4_bf16.
// ---------------------------------------------------------------------------
__global__ __launch_bounds__(512) void gemm_nt_splitk4(
    const unsigned short* __restrict__ A, const unsigned short* __restrict__ B,
    unsigned short* __restrict__ C0, unsigned short* __restrict__ C1,
    unsigned short* __restrict__ C2, unsigned short* __restrict__ C3,
    int M, int N, int K)
{
    __shared__ __align__(16) unsigned short As[2][128 * 32];
    __shared__ __align__(16) unsigned short Bs[2][128 * 32];
    const int tid  = threadIdx.x;        // 0..511
    const int lane = tid & 63;
    const int wave = tid >> 6;           // 0..7
    const int per  = gridDim.x >> 3;
    const int lg   = (blockIdx.x & 7) * per + (blockIdx.x >> 3);
    const int kh   = lg & 3;
    const int bmn  = lg >> 2;
    const int bm = (bmn & 15) * 128;
    const int bn = (bmn >> 4) * 128;
    const int wr = (wave >> 1) * 32;     // 4 wave-rows of 32
    const int wc = (wave & 1) * 64;      // 2 wave-cols of 64
    const int fr = lane & 15;
    const int kg = lane >> 4;
    const int Kq = K >> 2;               // 768 -> 24 steps
    const int kbase = kh * Kq;

    f32x4 acc[2][4] = {};

#define GSTAGE(buf, k0) do { \
    int e_  = tid; \
    int r_  = e_ >> 2; \
    int c8_ = (e_ & 3) * 8; \
    const unsigned short* ga_ = A + (size_t)(bm + r_) * K + (k0) + c8_; \
    const unsigned short* gb_ = B + (size_t)(bn + r_) * K + (k0) + c8_; \
    unsigned short* la_ = As[buf] + (size_t)(wave * 64) * 8; \
    unsigned short* lb_ = Bs[buf] + (size_t)(wave * 64) * 8; \
    __builtin_amdgcn_global_load_lds( \
        (const __attribute__((address_space(1))) void*)ga_, \
        (__attribute__((address_space(3))) void*)la_, 16, 0, 0); \
    __builtin_amdgcn_global_load_lds( \
        (const __attribute__((address_space(1))) void*)gb_, \
        (__attribute__((address_space(3))) void*)lb_, 16, 0, 0); \
} while (0)

    GSTAGE(0, kbase);
    __syncthreads();

    int cur = 0;
    for (int k0 = kbase; k0 < kbase + Kq; k0 += 32) {
        if (k0 + 32 < kbase + Kq) GSTAGE(cur ^ 1, k0 + 32);

        bf16x8 a[2], b[4];
        #pragma unroll
        for (int f = 0; f < 2; ++f)
            a[f] = *(const bf16x8*)&As[cur][(wr + f * 16 + fr) * 32 + kg * 8];
        #pragma unroll
        for (int f = 0; f < 4; ++f)
            b[f] = *(const bf16x8*)&Bs[cur][(wc + f * 16 + fr) * 32 + kg * 8];
        #pragma unroll
        for (int fm = 0; fm < 2; ++fm)
            #pragma unroll
            for (int fn = 0; fn < 4; ++fn)
                acc[fm][fn] = __builtin_amdgcn_mfma_f32_16x16x32_bf16(
                    a[fm], b[fn], acc[fm][fn], 0, 0, 0);

        __syncthreads();
        cur ^= 1;
    }
#undef GSTAGE

    unsigned short* C = (kh == 0) ? C0 : (kh == 1) ? C1 : (kh == 2) ? C2 : C3;
    #pragma unroll
    for (int fm = 0; fm < 2; ++fm)
        #pragma unroll
        for (int fn = 0; fn < 4; ++fn) {
            int col = bn + wc + fn * 16 + fr;
            #pragma unroll
            for (int i = 0; i < 4; ++i) {
                int row = bm + wr + fm * 16 + kg * 4 + i;
                C[(size_t)row * N + col] = f2bf(acc[fm][fn][i]);
            }
        }
}

// ---------------------------------------------------------------------------
// Per-group: a/b (fp32 side-store) -> g, beta; cumulative log-decay scan;
// writes cinc/cexc/barr. 24 blocks x 64 threads.
// ---------------------------------------------------------------------------
__global__ __launch_bounds__(64) void cumsum_pack(
    const float* __restrict__ ab32,
    const float* __restrict__ A_log, const float* __restrict__ dt_bias,
    float* __restrict__ cinc, float* __restrict__ cexc, float* __restrict__ barr)
{
    const int g = blockIdx.x;
    const int b = g / NH, h = g % NH;
    const int lane = threadIdx.x;
    const float nA = -expf(A_log[h]);
    const float db = dt_bias[h];
    float carry = 0.f;
    for (int c0 = 0; c0 < TT; c0 += 64) {
        int t = c0 + lane;
        size_t rbase = (size_t)(b*TT + t) * 12;
        float a  = ab32[rbase + h] + db;
        float sp = (a > 20.f) ? a : log1pf(expf(a));
        float gv = nA * sp;
        float bp = ab32[rbase + 6 + h];
        float x = gv;
        #pragma unroll
        for (int off = 1; off < 64; off <<= 1) {
            float n = __shfl_up(x, off);
            if (lane >= off) x += n;
        }
        float inc = carry + x;
        cinc[(size_t)g*TT + t] = inc;
        cexc[(size_t)g*TT + t] = inc - gv;
        barr[(size_t)g*TT + t] = 1.f / (1.f + expf(-bp));
        carry = __shfl(inc, 63);
    }
}

// ---------------------------------------------------------------------------
// Pointwise prep v2: barrier-free. 384 threads = 6 waves; wave h owns head h.
// ---------------------------------------------------------------------------
__global__ __launch_bounds__(384) void prep_norm(
    const unsigned short* __restrict__ qkvg,
    const float* __restrict__ decay, const float* __restrict__ D,
    const float* __restrict__ barr,
    unsigned short* __restrict__ qb, unsigned short* __restrict__ kb,
    unsigned short* __restrict__ bvb)
{
    const int row  = blockIdx.x;
    const int b    = row >> 9, t = row & 511;
    const int tid  = threadIdx.x;
    const int h    = tid >> 6;       // wave = head
    const int lane = tid & 63;

    size_t base = (size_t)row * QW + h * DK + lane * 4;
    ushort4 qu = *(const ushort4*)&qkvg[base];
    ushort4 ku = *(const ushort4*)&qkvg[base + OFF_K];
    float qv[4] = {b2f(qu.x), b2f(qu.y), b2f(qu.z), b2f(qu.w)};
    float kv[4] = {b2f(ku.x), b2f(ku.y), b2f(ku.z), b2f(ku.w)};
    const float coef = D[h] * (1.f / (1.f + expf(-decay[h])));
    float qc[4], kl[4];
    float sq = 0.f, sk = 0.f;
    #pragma unroll
    for (int i = 0; i < 4; ++i) {
        float ksil = kv[i] / (1.f + expf(-kv[i]));
        float qsil = qv[i] / (1.f + expf(-qv[i]));
        qc[i] = qsil - coef * ksil;
        kl[i] = ksil;
        sq += qc[i] * qc[i];
        sk += ksil * ksil;
    }
    #pragma unroll
    for (int off = 32; off >= 1; off >>= 1) {
        sq += __shfl_xor(sq, off);
        sk += __shfl_xor(sk, off);
    }
    float qinv = 0.0625f / fmaxf(sqrtf(sq), 1e-12f);
    float kinv = 1.f     / fmaxf(sqrtf(sk), 1e-12f);
    size_t gidx = (((size_t)(b*NH + h)) * TT + t) * DK + lane * 4;
    ushort4 qo, ko;
    qo.x = f2bf(qc[0]*qinv); qo.y = f2bf(qc[1]*qinv);
    qo.z = f2bf(qc[2]*qinv); qo.w = f2bf(qc[3]*qinv);
    ko.x = f2bf(kl[0]*kinv); ko.y = f2bf(kl[1]*kinv);
    ko.z = f2bf(kl[2]*kinv); ko.w = f2bf(kl[3]*kinv);
    *(ushort4*)&qb[gidx] = qo;
    *(ushort4*)&kb[gidx] = ko;

    const int jj0 = tid * 8;
    const int h2  = jj0 >> 9;
    const int dv  = jj0 & 511;
    float bt = barr[((size_t)(b*NH + h2)) * TT + t];
    const unsigned short* vp = &qkvg[(size_t)row * QW + OFF_V + jj0];
    unsigned short* bp = &bvb[(((size_t)(b*NH + h2)) * TT + t) * DV + dv];
    ushort4 v0 = *(const ushort4*)vp;
    ushort4 v1 = *(const ushort4*)(vp + 4);
    unsigned short vi[8] = {v0.x, v0.y, v0.z, v0.w, v1.x, v1.y, v1.z, v1.w};
    ushort4 o0, o1;
    unsigned short vo[8];
    #pragma unroll
    for (int i = 0; i < 8; ++i) {
        float xv = b2f(vi[i]);
        float sv = xv / (1.f + expf(-xv));
        vo[i] = f2bf(bt * sv);
    }
    o0.x = vo[0]; o0.y = vo[1]; o0.z = vo[2]; o0.w = vo[3];
    o1.x = vo[4]; o1.y = vo[5]; o1.z = vo[6]; o1.w = vo[7];
    *(ushort4*)bp       = o0;
    *(ushort4*)(bp + 4) = o1;
}

// ---------------------------------------------------------------------------
// A-matrix tiles: A[i,j] = beta_i * exp(cexc_i - cinc_j) * (k_i . k_j), j<i.
// Diagonal blocks (l==m) ALSO compute the unit-lower-triangular inverse of
// (I + A_mm) in-kernel (fused minv).
// ---------------------------------------------------------------------------
__global__ __launch_bounds__(256) void a_mat(
    const unsigned short* __restrict__ kb, const float* __restrict__ cinc,
    const float* __restrict__ cexc, const float* __restrict__ barr,
    unsigned short* __restrict__ Ab, unsigned short* __restrict__ Minvb)
{
    __shared__ __align__(16) unsigned short Asub[64][72];
    __shared__ __align__(16) float Xt[64][68];

    const int blk = blockIdx.x;
    const int g = blk / 36;
    int p = blk % 36, m = 0, acc0 = 0;
    while (p >= acc0 + m + 1) { acc0 += m + 1; ++m; }
    const int l = p - acc0;
    const int tid = threadIdx.x, lane = tid & 63, w = tid >> 6;
    const int fr = lane & 15, kg = lane >> 4;
    const unsigned short* Km = kb + (((size_t)g*TT) + m*CL) * DK;
    const unsigned short* Kl = kb + (((size_t)g*TT) + l*CL) * DK;
    f32x4 acc[4] = {};
    #pragma unroll
    for (int ks = 0; ks < 8; ++ks) {
        bf16x8 a = *(const bf16x8*)(Km + (size_t)(w*16 + fr)*DK + ks*32 + kg*8);
        bf16x8 bb[4];
        #pragma unroll
        for (int fn = 0; fn < 4; ++fn)
            bb[fn] = *(const bf16x8*)(Kl + (size_t)(fn*16 + fr)*DK + ks*32 + kg*8);
        #pragma unroll
        for (int fn = 0; fn < 4; ++fn)
            acc[fn] = __builtin_amdgcn_mfma_f32_16x16x32_bf16(a, bb[fn], acc[fn], 0, 0, 0);
    }
    const float* ci = cinc + (size_t)g*TT;
    const float* ce = cexc + (size_t)g*TT;
    const float* bb2 = barr + (size_t)g*TT;
    const bool diag = (l == m);
    #pragma unroll
    for (int fn = 0; fn < 4; ++fn) {
        int jl = fn*16 + fr;
        int tj = l*CL + jl;
        float cj = ci[tj];
        #pragma unroll
        for (int r = 0; r < 4; ++r) {
            int il = w*16 + kg*4 + r;
            int ti = m*CL + il;
            float val = 0.f;
            if (tj < ti) val = bb2[ti] * __expf(ce[ti] - cj) * acc[fn][r];
            unsigned short vb = f2bf(val);
            Ab[((size_t)g*TT + ti)*TT + tj] = vb;
            if (diag) Asub[il][jl] = vb;
        }
    }

    if (diag) {
        __syncthreads();                 // Asub staged by all 4 waves
        if (tid < 64) {                  // wave 0: wave-synchronous inverse
            const int col = tid;
            #pragma unroll
            for (int t4 = 0; t4 < 17; ++t4)
                *(float4*)&Xt[col][t4*4] = make_float4(0.f, 0.f, 0.f, 0.f);
            Xt[col][col] = 1.f;
            #pragma unroll 1
            for (int i = 1; i < 64; ++i) {
                const int nch = (i + 7) >> 3;
                float s = 0.f;
                #pragma unroll 1
                for (int c8 = 0; c8 < nch; ++c8) {
                    ushort4 a0 = *(const ushort4*)&Asub[i][c8*8];
                    ushort4 a1 = *(const ushort4*)&Asub[i][c8*8 + 4];
                    float4  x0 = *(const float4*)&Xt[col][c8*8];
                    float4  x1 = *(const float4*)&Xt[col][c8*8 + 4];
                    s += b2f(a0.x)*x0.x; s += b2f(a0.y)*x0.y;
                    s += b2f(a0.z)*x0.z; s += b2f(a0.w)*x0.w;
                    s += b2f(a1.x)*x1.x; s += b2f(a1.y)*x1.y;
                    s += b2f(a1.z)*x1.z; s += b2f(a1.w)*x1.w;
                }
                if (col < i) Xt[col][i] = -s;
            }
            unsigned short* outp = Minvb + (size_t)(g*8 + m) * 4096;
            #pragma unroll 4
            for (int r = 0; r < 64; ++r)
                outp[(size_t)r*64 + col] = f2bf(Xt[col][r]);
        }
    }
}

// ---------------------------------------------------------------------------
// U-solve v3: (I+A) U = beta*V, block forward substitution over 8 chunks.
// grid = 24 groups x 16 v-slices(32) = 384 blocks. Utb[g][v][t] bf16.
// Block's whole U slice mirrored in LDS (Uls[32][520]); all chunk-to-chunk
// U reads come from LDS (no global RAW round-trips). Bit-identical.
// ---------------------------------------------------------------------------
__global__ __launch_bounds__(256) void usolve(
    const unsigned short* __restrict__ Ab, const unsigned short* __restrict__ Minvb,
    const unsigned short* __restrict__ bvb, unsigned short* __restrict__ Utb)
{
    const int blk = blockIdx.x;
    const int g = blk >> 4, vs = blk & 15;
    const int tid = threadIdx.x, lane = tid & 63, w = tid >> 6;
    const int fr = lane & 15, kg = lane >> 4;
    __shared__ __align__(16) unsigned short TACC[2][32][40];
    __shared__ __align__(16) unsigned short Uls[32][520];   // [v][t], pad->2-way

    for (int m = 0; m < NC; ++m) {
        f32x4 acc[2] = {};
        for (int l = 0; l < m; ++l) {
            const unsigned short* Aml = Ab + (((size_t)g*TT) + m*CL)*TT + l*CL;
            #pragma unroll
            for (int ks = 0; ks < 2; ++ks) {
                bf16x8 a = *(const bf16x8*)(Aml + (size_t)(w*16 + fr)*TT + ks*32 + kg*8);
                bf16x8 bb[2];
                #pragma unroll
                for (int fn = 0; fn < 2; ++fn)
                    bb[fn] = *(const bf16x8*)&Uls[fn*16 + fr][l*CL + ks*32 + kg*8];
                #pragma unroll
                for (int fn = 0; fn < 2; ++fn)
                    acc[fn] = __builtin_amdgcn_mfma_f32_16x16x32_bf16(a, bb[fn], acc[fn], 0, 0, 0);
            }
        }
        __syncthreads();
        const unsigned short* bvg = bvb + (((size_t)g*TT) + m*CL)*DV + vs*32;
        #pragma unroll
        for (int fn = 0; fn < 2; ++fn) {
            int v = fn*16 + fr;
            #pragma unroll
            for (int r = 0; r < 4; ++r) {
                int i = w*16 + kg*4 + r;
                float rhs = b2f(bvg[(size_t)i*DV + v]) - acc[fn][r];
                TACC[i >> 5][v][i & 31] = f2bf(rhs);
            }
        }
        __syncthreads();
        const unsigned short* Mi = Minvb + (size_t)(g*8 + m) * 4096;
        f32x4 acc2[2] = {};
        #pragma unroll
        for (int ks = 0; ks < 2; ++ks) {
            bf16x8 a = *(const bf16x8*)(Mi + (size_t)(w*16 + fr)*64 + ks*32 + kg*8);
            bf16x8 bb[2];
            #pragma unroll
            for (int fn = 0; fn < 2; ++fn)
                bb[fn] = *(const bf16x8*)&TACC[ks][fn*16 + fr][kg*8];
            #pragma unroll
            for (int fn = 0; fn < 2; ++fn)
                acc2[fn] = __builtin_amdgcn_mfma_f32_16x16x32_bf16(a, bb[fn], acc2[fn], 0, 0, 0);
        }
        unsigned short* Um = Utb + (((size_t)g*TT) + vs*32)*TT + m*CL;
        #pragma unroll
        for (int fn = 0; fn < 2; ++fn) {
            int v = fn*16 + fr;
            #pragma unroll
            for (int r = 0; r < 4; ++r) {
                int i = w*16 + kg*4 + r;
                unsigned short uv = f2bf(acc2[fn][r]);
                Um[(size_t)v*TT + i] = uv;          // for o_kern
                Uls[v][m*CL + i]    = uv;           // for later chunks (LDS)
            }
        }
        __syncthreads();   // LDS U-chunk visible before next chunk reads it
    }
}

// ---------------------------------------------------------------------------
// Output: o_i = sum_{j<=i} exp(c_i - c_j)*(q_i . k_j) * u_j.
// Block = (g, m-pair {p, 7-p}, v-quarter 128). 9 balanced l-iters per block.
// K/U tiles async-staged into double-buffered swizzled LDS; Q in registers.
// Writes o bf16 into the fused qkvg buffer's (dead) v columns @3072.
// ---------------------------------------------------------------------------
__global__ __launch_bounds__(256) void o_kern(
    const unsigned short* __restrict__ qb, const unsigned short* __restrict__ kb,
    const unsigned short* __restrict__ Utb, const float* __restrict__ cinc,
    unsigned short* __restrict__ qkvg)
{
    __shared__ __align__(16) unsigned short Kls[2][64*256];   // 64 KB
    __shared__ __align__(16) unsigned short Uls[2][128*64];   // 32 KB
    __shared__ __align__(16) unsigned short Ps[2][64][40];    // 10 KB
    __shared__ float cgl[TT];                                 // 2 KB

    const int blk = blockIdx.x;
    const int g  = blk >> 4;
    const int rm = blk & 15;
    const int pr = rm >> 2;
    const int vq = rm & 3;
    const int b = g / NH, h = g % NH;
    const int tid = threadIdx.x, lane = tid & 63, w = tid >> 6;
    const int fr = lane & 15, kg = lane >> 4;

    const unsigned short* kgrp = kb  + (size_t)g*TT*DK;
    const unsigned short* ugrp = Utb + ((size_t)g*TT + vq*128)*TT;

#define STAGE_K(buf, l) do { \
    _Pragma("unroll") \
    for (int s_ = 0; s_ < 8; ++s_) { \
        int slot_ = s_*256 + tid; \
        int gc_ = slot_ ^ ((slot_ >> 5) & 7); \
        const unsigned short* ga_ = kgrp + (size_t)(l)*CL*DK + gc_*8; \
        __builtin_amdgcn_global_load_lds( \
            (const __attribute__((address_space(1))) void*)ga_, \
            (__attribute__((address_space(3))) void*)&Kls[buf][slot_*8], 16, 0, 0); \
    } \
} while (0)

#define STAGE_U(buf, l) do { \
    _Pragma("unroll") \
    for (int s_ = 0; s_ < 4; ++s_) { \
        int slot_ = s_*256 + tid; \
        int gc_ = slot_ ^ ((slot_ >> 3) & 7); \
        const unsigned short* ga_ = ugrp + (size_t)(gc_ >> 3)*TT + (l)*CL + (gc_ & 7)*8; \
        __builtin_amdgcn_global_load_lds( \
            (const __attribute__((address_space(1))) void*)ga_, \
            (__attribute__((address_space(3))) void*)&Uls[buf][slot_*8], 16, 0, 0); \
    } \
} while (0)

    cgl[tid]       = cinc[(size_t)g*TT + tid];
    cgl[tid + 256] = cinc[(size_t)g*TT + tid + 256];
    STAGE_K(0, 0);
    STAGE_U(0, 0);
    __syncthreads();

    int cur = 0;
    #pragma unroll 1
    for (int mi_idx = 0; mi_idx < 2; ++mi_idx) {
        const int mi = mi_idx ? (7 - pr) : pr;
        const unsigned short* Qm = qb + (((size_t)g*TT) + mi*CL) * DK + (size_t)(w*16 + fr)*DK;
        bf16x8 qf[8];
        #pragma unroll
        for (int ks = 0; ks < 8; ++ks) qf[ks] = *(const bf16x8*)(Qm + ks*32 + kg*8);

        f32x4 acc[8] = {};
        #pragma unroll 1
        for (int l = 0; l <= mi; ++l) {
            if (l < mi)            { STAGE_K(cur^1, l+1); STAGE_U(cur^1, l+1); }
            else if (mi_idx == 0)  { STAGE_K(cur^1, 0);   STAGE_U(cur^1, 0);   }

            f32x4 sacc[4] = {};
            #pragma unroll
            for (int ks = 0; ks < 8; ++ks) {
                bf16x8 bbf[4];
                #pragma unroll
                for (int fn = 0; fn < 4; ++fn) {
                    int row = fn*16 + fr;
                    int slot = (row*32 + ks*4 + kg) ^ (row & 7);
                    bbf[fn] = *(const bf16x8*)&Kls[cur][slot*8];
                }
                #pragma unroll
                for (int fn = 0; fn < 4; ++fn)
                    sacc[fn] = __builtin_amdgcn_mfma_f32_16x16x32_bf16(qf[ks], bbf[fn], sacc[fn], 0, 0, 0);
            }
            __syncthreads();

            #pragma unroll
            for (int fn = 0; fn < 4; ++fn) {
                int jl = fn*16 + fr;
                float cjv = cgl[l*CL + jl];
                #pragma unroll
                for (int r = 0; r < 4; ++r) {
                    int il = w*16 + kg*4 + r;
                    float val = ((l*CL + jl) <= (mi*CL + il))
                              ? sacc[fn][r] * __expf(cgl[mi*CL + il] - cjv) : 0.f;
                    Ps[jl >> 5][il][jl & 31] = f2bf(val);
                }
            }
            __syncthreads();

            #pragma unroll
            for (int ks = 0; ks < 2; ++ks) {
                bf16x8 a = *(const bf16x8*)&Ps[ks][w*16 + fr][kg*8];
                bf16x8 bbf[8];
                #pragma unroll
                for (int fn = 0; fn < 8; ++fn) {
                    int vrow = fn*16 + fr;
                    int slot = (vrow*8 + ks*4 + kg) ^ (vrow & 7);
                    bbf[fn] = *(const bf16x8*)&Uls[cur][slot*8];
                }
                #pragma unroll
                for (int fn = 0; fn < 8; ++fn)
                    acc[fn] = __builtin_amdgcn_mfma_f32_16x16x32_bf16(a, bbf[fn], acc[fn], 0, 0, 0);
            }
            __syncthreads();
            cur ^= 1;
        }

        // store o (bf16) into fused buffer (dead v columns): [row][QW]@3072
        unsigned short* ob = qkvg + ((size_t)(b*TT + mi*CL)) * QW + OFF_V + h*DV + vq*128;
        #pragma unroll
        for (int fn = 0; fn < 8; ++fn) {
            int v = fn*16 + fr;
            #pragma unroll
            for (int r = 0; r < 4; ++r) {
                int il = w*16 + kg*4 + r;
                ob[(size_t)il*QW + v] = f2bf(acc[fn][r]);
            }
        }
    }
#undef STAGE_K
#undef STAGE_U
}

// ---------------------------------------------------------------------------
// Gated RMSNorm epilogue v2: barrier-free. 384 threads = 6 waves; wave h owns
// head h: 8 elems/lane, wave-local shfl reduction, 16B loads/stores.
// ---------------------------------------------------------------------------
__global__ __launch_bounds__(384) void epilogue(
    const unsigned short* __restrict__ qkvg, const float* __restrict__ wnorm,
    unsigned short* __restrict__ ob)
{
    const int row  = blockIdx.x;
    const int tid  = threadIdx.x;
    const int h    = tid >> 6;
    const int lane = tid & 63;

    size_t base = (size_t)row * QW + OFF_V + h * DV + lane * 8;
    ushort4 a0 = *(const ushort4*)&qkvg[base];
    ushort4 a1 = *(const ushort4*)&qkvg[base + 4];
    unsigned short oi[8] = {a0.x, a0.y, a0.z, a0.w, a1.x, a1.y, a1.z, a1.w};
    float ov[8];
    float ss = 0.f;
    #pragma unroll
    for (int i = 0; i < 8; ++i) { ov[i] = b2f(oi[i]); ss += ov[i]*ov[i]; }
    #pragma unroll
    for (int off = 32; off >= 1; off >>= 1) ss += __shfl_xor(ss, off);
    float irms = rsqrtf(ss * (1.f / DV) + 1e-6f);

    size_t gbase = (size_t)row * QW + OFF_G + h * DV + lane * 8;
    ushort4 g0 = *(const ushort4*)&qkvg[gbase];
    ushort4 g1 = *(const ushort4*)&qkvg[gbase + 4];
    unsigned short gi[8] = {g0.x, g0.y, g0.z, g0.w, g1.x, g1.y, g1.z, g1.w};

    unsigned short vo[8];
    #pragma unroll
    for (int i = 0; i < 8; ++i) {
        float gv = b2f(gi[i]);
        float wv = wnorm[lane*8 + i];
        vo[i] = f2bf(ov[i] * irms * wv * (1.f / (1.f + expf(-gv))));
    }
    size_t obase = (size_t)row * VAL_DIM + h * DV + lane * 8;
    ushort4 w0, w1;
    w0.x = vo[0]; w0.y = vo[1]; w0.z = vo[2]; w0.w = vo[3];
    w1.x = vo[4]; w1.y = vo[5]; w1.z = vo[6]; w1.w = vo[7];
    *(ushort4*)&ob[obase]     = w0;
    *(ushort4*)&ob[obase + 4] = w1;
}

// ---------------------------------------------------------------------------
extern "C" void kernel_launch(void* const* d_in, const int* in_sizes, int n_in,
                              void* d_out, int out_size, void* d_ws, size_t ws_size,
                              hipStream_t stream)
{
    const float* x     = (const float*)d_in[0];
    const float* Wq    = (const float*)d_in[1];
    const float* Wk    = (const float*)d_in[2];
    const float* Wv    = (const float*)d_in[3];
    const float* Wa    = (const float*)d_in[4];
    const float* Wb    = (const float*)d_in[5];
    const float* decay = (const float*)d_in[6];
    const float* Dp    = (const float*)d_in[7];
    const float* A_log = (const float*)d_in[8];
    const float* dtb   = (const float*)d_in[9];
    const float* Wg    = (const float*)d_in[10];
    const float* Wo    = (const float*)d_in[11];
    const float* onw   = (const float*)d_in[12];
    float* out = (float*)d_out;

    unsigned short* qkvg = (unsigned short*)d_ws;            // ROWS*QW bf16 (38.3 MB)
    float* ab32 = (float*)(qkvg + (size_t)ROWS * QW);        // ROWS*12 fp32 (a|b cols)
    float* cinc = ab32 + (size_t)ROWS * 12;                  // NG*TT
    float* cexc = cinc + (size_t)NG * TT;
    float* barr = cexc + (size_t)NG * TT;
    unsigned short* bf = (unsigned short*)(barr + (size_t)NG * TT);

    // phase 1 (projections): weight block is one contiguous [9344][2048]
    // bf16 matrix (order q,k,v,g,a,b,zero-pad).
    unsigned short* xb  = bf;                                   // ROWS*HID
    unsigned short* Wqb = xb  + (size_t)ROWS * HID;
    // phase R (chunked recurrence) — aliases phase 1 (dead by then)
    unsigned short* qb    = bf;                                 // NG*TT*DK
    unsigned short* kb    = qb  + (size_t)NG*TT*DK;
    unsigned short* bvb   = kb  + (size_t)NG*TT*DK;             // NG*TT*DV
    unsigned short* Ab    = bvb + (size_t)NG*TT*DV;             // NG*TT*TT
    unsigned short* Utb   = Ab  + (size_t)NG*TT*TT;             // NG*TT*TT (transposed)
    unsigned short* Minvb = Utb + (size_t)NG*TT*TT;             // NG*8*64*64
    // phase 2 (output projection): ob aliases qb+kb; Wob aliases bvb;
    // bf16 partials P0..P3 alias Ab onward (dead after o_kern).
    unsigned short* ob  = bf;                                   // ROWS*VAL_DIM
    unsigned short* Wob = bvb;                                  // HID*VAL_DIM
    unsigned short* P0 = Ab;                                    // 4 x ROWS*HID bf16
    unsigned short* P1 = P0 + (size_t)ROWS * HID;
    unsigned short* P2 = P1 + (size_t)ROWS * HID;
    unsigned short* P3 = P2 + (size_t)ROWS * HID;

    dim3 blk(256);
    auto cblocks = [](size_t n) { size_t b = (n / 4 + 255) / 256; return (int)(b > 4096 ? 4096 : b); };

    // fused cast: x|Wq|Wk|Wv|Wg|Wa|Wb|pad -> contiguous bf16 block at xb
    Cast8 c8;
    c8.src[0] = x;  c8.src[1] = Wq; c8.src[2] = Wk; c8.src[3] = Wv;
    c8.src[4] = Wg; c8.src[5] = Wa; c8.src[6] = Wb; c8.src[7] = nullptr;
    c8.start4[0] = 0;
    c8.start4[1] = c8.start4[0] + ROWS*HID/4;
    c8.start4[2] = c8.start4[1] + KEY_DIM*HID/4;
    c8.start4[3] = c8.start4[2] + KEY_DIM*HID/4;
    c8.start4[4] = c8.start4[3] + VAL_DIM*HID/4;
    c8.start4[5] = c8.start4[4] + VAL_DIM*HID/4;
    c8.start4[6] = c8.start4[5] + NH*HID/4;
    c8.start4[7] = c8.start4[6] + NH*HID/4;
    c8.start4[8] = c8.start4[7] + (QW - OFF_A - 12)*HID/4;   // 116-row zero pad
    cast_multi<<<dim3(2048), blk, 0, stream>>>(c8, xb);

    // fused q|k|v|gate|a|b projection: 1168 blocks, 8-wave 2-phase template
    gemm_qkvg<<<dim3((QW/128) * (ROWS/128)), dim3(512), 0, stream>>>(
        xb, Wqb, qkvg, ab32, ROWS, QW, HID);

    cumsum_pack<<<dim3(NG), dim3(64), 0, stream>>>(ab32, A_log, dtb, cinc, cexc, barr);
    prep_norm<<<dim3(ROWS), dim3(384), 0, stream>>>(qkvg, decay, Dp, barr, qb, kb, bvb);
    a_mat<<<dim3(NG*36), blk, 0, stream>>>(kb, cinc, cexc, barr, Ab, Minvb);  // fused minv
    usolve<<<dim3(NG*16), blk, 0, stream>>>(Ab, Minvb, bvb, Utb);
    o_kern<<<dim3(NG*16), blk, 0, stream>>>(qb, kb, Utb, cinc, qkvg);
    epilogue<<<dim3(ROWS), dim3(384), 0, stream>>>(qkvg, onw, ob);

    // output projection: split-K=4, 1024 blocks, 8-wave template,
    // bf16 partials + fp32 reduce
    cast_f32_bf16<<<cblocks((size_t)HID*VAL_DIM), blk, 0, stream>>>(Wo, Wob, HID*VAL_DIM/4);
    gemm_nt_splitk4<<<dim3(4 * (HID/128) * (ROWS/128)), dim3(512), 0, stream>>>(
        ob, Wob, P0, P1, P2, P3, ROWS, HID, VAL_DIM);
    add4_bf16<<<dim3(2048), blk, 0, stream>>>(out, P0, P1, P2, P3, ROWS*HID/4);
}